// Round 1
// baseline (16690.668 us; speedup 1.0000x reference)
//
#include <hip/hip_runtime.h>
#include <cstdint>

#define NB 8
#define CIN 1024
#define HDIM 50
#define WDIM 50
#define COUT 512
#define NA 9
#define NANCH (HDIM*WDIM*NA)   /* 22500 */
#define PRE_N 2000
#define POST_N 100

// ---------------- workspace layout (bytes) ----------------
constexpr size_t OFF_T     = 0;                          // 8*50*50*512 f32 = 40,960,000 (layout b,h,w,co)
constexpr size_t OFF_BOXES = 40960000;                   // 8*22500*4 f32
constexpr size_t OFF_MS    = OFF_BOXES + 2880000;        // 8*22500 f32 (masked scores)
constexpr size_t OFF_KEYS  = OFF_MS + 720000;            // 8*22500 u64
constexpr size_t OFF_TBOX  = OFF_KEYS + 1440000;         // 8*2000*4 f32
constexpr size_t OFF_TS    = OFF_TBOX + 256000;          // 8*2000 f32
constexpr size_t OFF_SUP   = OFF_TS + 64000;             // 8*2000*32 u64 (suppression bits)
constexpr size_t OFF_KEEP  = OFF_SUP + 4096000;          // 8*64 u32

// ---------------- conv 3x3 + bias + relu ----------------
// block: 256 thr; thread t: co_local = t&127, half = t>>7 (w0 = half*25)
// grid: ((b*50 + h)*4 + co_tile), co_tile in [0,4)
#define KC 8
#define CO_TILE 128
__global__ __launch_bounds__(256) void conv_kernel(const float* __restrict__ f,
                                                   const float* __restrict__ W1,
                                                   const float* __restrict__ b1,
                                                   float* __restrict__ tout) {
    int blk = blockIdx.x;
    int cot = blk & 3;
    int h   = (blk >> 2) % HDIM;
    int b   = blk / (HDIM * 4);
    int co0 = cot * CO_TILE;

    __shared__ float sh_in[KC][3][52];        // 4,992 B  (col index = w+1, zero halo)
    __shared__ float sh_w[CO_TILE][73];       // 37,376 B (72 used, +1 pad)

    int t = threadIdx.x;
    int co_l = t & 127;
    int half = t >> 7;
    int w0 = half * 25;

    float acc[25];
#pragma unroll
    for (int j = 0; j < 25; ++j) acc[j] = 0.f;

    for (int ci0 = 0; ci0 < CIN; ci0 += KC) {
        __syncthreads();
        // stage inputs: rows h-1..h+1, cols -1..50 (zero pad)
        for (int idx = t; idx < KC * 3 * 52; idx += 256) {
            int ci  = idx / 156;
            int rem = idx - ci * 156;
            int r   = rem / 52;
            int col = rem - r * 52;      // 0..51  -> w = col-1
            int hh  = h - 1 + r;
            int w   = col - 1;
            float v = 0.f;
            if (hh >= 0 && hh < HDIM && w >= 0 && w < WDIM)
                v = f[(((size_t)b * CIN + ci0 + ci) * HDIM + hh) * WDIM + w];
            sh_in[ci][r][col] = v;
        }
        // stage weights: 128 co x 72 (8ci*9)
        for (int idx = t; idx < CO_TILE * 72; idx += 256) {
            int co = idx / 72;
            int k  = idx - co * 72;
            sh_w[co][k] = W1[(size_t)(co0 + co) * (CIN * 9) + ci0 * 9 + k];
        }
        __syncthreads();

#pragma unroll
        for (int ci = 0; ci < KC; ++ci) {
#pragma unroll
            for (int kh = 0; kh < 3; ++kh) {
                float rr[27];
#pragma unroll
                for (int x = 0; x < 27; ++x) rr[x] = sh_in[ci][kh][w0 + x];
#pragma unroll
                for (int kw = 0; kw < 3; ++kw) {
                    float wv = sh_w[co_l][ci * 9 + kh * 3 + kw];
#pragma unroll
                    for (int j = 0; j < 25; ++j)
                        acc[j] = fmaf(rr[j + kw], wv, acc[j]);
                }
            }
        }
    }

    float bv = b1[co0 + co_l];
    size_t base = ((size_t)b * HDIM + h) * WDIM;
#pragma unroll
    for (int j = 0; j < 25; ++j) {
        float v = acc[j] + bv;
        v = v > 0.f ? v : 0.f;
        tout[(base + (w0 + j)) * COUT + co0 + co_l] = v;   // layout (b,h,w,co), coalesced over co
    }
}

// ---------------- projection + decode + key build ----------------
// grid: b*50 + h ; 256 threads
__global__ __launch_bounds__(256) void proj_decode_kernel(const float* __restrict__ tin,
                                                          const float* __restrict__ W2,
                                                          const float* __restrict__ b2,
                                                          const float* __restrict__ W3,
                                                          const float* __restrict__ b3,
                                                          float* __restrict__ boxes,
                                                          float* __restrict__ mscores,
                                                          unsigned long long* __restrict__ keys) {
    int blk = blockIdx.x;           // b*50+h
    int b = blk / HDIM;
    int h = blk % HDIM;
    int t = threadIdx.x;

    __shared__ float sw[45 * 65];    // 45 rows x 64ch chunk (pad 65)
    __shared__ float tch[50 * 65];   // 50 px x 64ch chunk
    __shared__ float pout[50 * 46];  // 45 outputs per pixel (pad 46)

    float acc[9];
#pragma unroll
    for (int k = 0; k < 9; ++k) acc[k] = 0.f;

    size_t tbase = (size_t)blk * (WDIM * COUT);

    for (int c0 = 0; c0 < COUT; c0 += 64) {
        __syncthreads();
        for (int idx = t; idx < 50 * 64; idx += 256) {
            int px = idx >> 6, c = idx & 63;
            tch[px * 65 + c] = tin[tbase + (size_t)px * COUT + c0 + c];
        }
        for (int idx = t; idx < 45 * 64; idx += 256) {
            int o = idx >> 6, c = idx & 63;
            float v = (o < 36) ? W2[o * COUT + c0 + c] : W3[(o - 36) * COUT + c0 + c];
            sw[o * 65 + c] = v;
        }
        __syncthreads();
#pragma unroll
        for (int k = 0; k < 9; ++k) {
            int id = t + k * 256;
            if (id < 2250) {
                int px = id / 45;
                int o  = id - px * 45;
                float s = acc[k];
                for (int c = 0; c < 64; ++c)
                    s = fmaf(tch[px * 65 + c], sw[o * 65 + c], s);
                acc[k] = s;
            }
        }
    }
    __syncthreads();
#pragma unroll
    for (int k = 0; k < 9; ++k) {
        int id = t + k * 256;
        if (id < 2250) {
            int px = id / 45;
            int o  = id - px * 45;
            float bias = (o < 36) ? b2[o] : b3[o - 36];
            pout[px * 46 + o] = acc[k] + bias;
        }
    }
    __syncthreads();

    // decode: 50 px * 9 anchors
    const float AW[9] = {90.50966799187809f, 128.0f, 181.01933598375618f,
                         181.01933598375618f, 256.0f, 362.03867196751236f,
                         362.03867196751236f, 512.0f, 724.0773439350247f};
    const float AH[9] = {181.01933598375618f, 128.0f, 90.50966799187809f,
                         362.03867196751236f, 256.0f, 181.01933598375618f,
                         724.0773439350247f, 512.0f, 362.03867196751236f};
    const float CLIPV = 4.135166556742356f;  // log(1000/16)
    const float IMG = 1600.0f;

    for (int id = t; id < 450; id += 256) {
        int px = id / 9;
        int a  = id - px * 9;
        float tx = pout[px * 46 + a * 4 + 0];
        float ty = pout[px * 46 + a * 4 + 1];
        float tw = pout[px * 46 + a * 4 + 2];
        float th = pout[px * 46 + a * 4 + 3];
        float lg = pout[px * 46 + 36 + a];

        float s = 1.0f / (1.0f + expf(-lg));

        float cx = ((float)px + 0.5f) * 32.0f;
        float cy = ((float)h + 0.5f) * 32.0f;
        // replicate reference rounding: build corners, re-derive wa/cxa
        float x1a = cx - 0.5f * AW[a];
        float x2a = cx + 0.5f * AW[a];
        float y1a = cy - 0.5f * AH[a];
        float y2a = cy + 0.5f * AH[a];
        float waf = x2a - x1a;
        float haf = y2a - y1a;
        float cxa = x1a + 0.5f * waf;
        float cya = y1a + 0.5f * haf;

        float twc = tw < CLIPV ? tw : CLIPV;
        float thc = th < CLIPV ? th : CLIPV;
        float pxc = tx * waf + cxa;
        float pyc = ty * haf + cya;
        float pw  = expf(twc) * waf;
        float ph  = expf(thc) * haf;

        float x1 = pxc - 0.5f * pw;
        float y1 = pyc - 0.5f * ph;
        float x2 = pxc + 0.5f * pw;
        float y2 = pyc + 0.5f * ph;
        x1 = fminf(fmaxf(x1, 0.f), IMG);
        y1 = fminf(fmaxf(y1, 0.f), IMG);
        x2 = fminf(fmaxf(x2, 0.f), IMG);
        y2 = fminf(fmaxf(y2, 0.f), IMG);

        float bw = x2 - x1, bh = y2 - y1;
        bool valid = (s >= 0.1f) && (bw > 16.0f) && (bh > 16.0f);
        float m = valid ? s : -1.0f;

        int idx = (h * WDIM + px) * NA + a;
        size_t gi = (size_t)b * NANCH + idx;
        float4 bx = make_float4(x1, y1, x2, y2);
        ((float4*)boxes)[gi] = bx;
        mscores[gi] = m;
        unsigned int u = __float_as_uint(m);
        unsigned int k32 = (u & 0x80000000u) ? ~u : (u | 0x80000000u);
        keys[gi] = ((unsigned long long)k32 << 32) | (unsigned long long)(0xFFFFFFFFu - (unsigned)idx);
    }
}

// ---------------- exact stable top-2000 (radix select + bitonic) ----------------
// grid: 8 blocks (one per batch), 256 threads
__global__ __launch_bounds__(256) void select_sort_kernel(const unsigned long long* __restrict__ keys,
                                                          const float* __restrict__ boxes,
                                                          const float* __restrict__ mscores,
                                                          float* __restrict__ top_boxes,
                                                          float* __restrict__ top_s) {
    int b = blockIdx.x;
    int t = threadIdx.x;
    const unsigned long long* kb = keys + (size_t)b * NANCH;

    __shared__ unsigned int hist[2048];
    __shared__ unsigned int gs[256];
    __shared__ int s_chosen, s_rnew;
    __shared__ unsigned int s_cnt;
    __shared__ unsigned long long skeys[2048];

    const int widths[6] = {11, 11, 11, 11, 11, 9};
    unsigned long long prefix = 0;
    int bitsdone = 0;
    int r = PRE_N;

    for (int p = 0; p < 6; ++p) {
        int width = widths[p];
        int bins = 1 << width;
        int shift = 64 - bitsdone - width;
        for (int i = t; i < bins; i += 256) hist[i] = 0;
        __syncthreads();
        for (int i = t; i < NANCH; i += 256) {
            unsigned long long k = kb[i];
            bool ok = (bitsdone == 0) || ((k >> (64 - bitsdone)) == prefix);
            if (ok) atomicAdd(&hist[(unsigned)((k >> shift) & (unsigned long long)(bins - 1))], 1u);
        }
        __syncthreads();
        int G = bins / 256;
        unsigned int gsum = 0;
        for (int g = 0; g < G; ++g) gsum += hist[t * G + g];
        gs[t] = gsum;
        __syncthreads();
        if (t == 0) {
            int acc = 0, chosen = 0, rnew = 1;
            for (int g = 255; g >= 0; --g) {
                int sgv = (int)gs[g];
                if (acc + sgv >= r) {
                    for (int d = g * G + G - 1; d >= g * G; --d) {
                        int hv = (int)hist[d];
                        if (acc + hv >= r) { chosen = d; rnew = r - acc; break; }
                        acc += hv;
                    }
                    break;
                }
                acc += sgv;
            }
            s_chosen = chosen;
            s_rnew = rnew;
        }
        __syncthreads();
        prefix = (prefix << width) | (unsigned long long)s_chosen;
        bitsdone += width;
        r = s_rnew;
        __syncthreads();
    }
    unsigned long long Kst = prefix;   // exact rank-2000 key

    if (t == 0) s_cnt = 0;
    __syncthreads();
    for (int i = t; i < NANCH; i += 256) {
        unsigned long long k = kb[i];
        if (k >= Kst) {
            unsigned int p = atomicAdd(&s_cnt, 1u);
            if (p < 2048) skeys[p] = k;
        }
    }
    __syncthreads();
    unsigned int cnt = s_cnt;
    for (int i = t; i < 2048; i += 256)
        if (i >= (int)cnt) skeys[i] = 0ull;
    // bitonic sort, descending
    for (int k = 2; k <= 2048; k <<= 1) {
        for (int j = k >> 1; j > 0; j >>= 1) {
            __syncthreads();
            for (int i = t; i < 2048; i += 256) {
                int l = i ^ j;
                if (l > i) {
                    unsigned long long a = skeys[i], c = skeys[l];
                    bool up = ((i & k) == 0);
                    if (up ? (a < c) : (a > c)) { skeys[i] = c; skeys[l] = a; }
                }
            }
        }
    }
    __syncthreads();
    // gather top 2000
    for (int i = t; i < PRE_N; i += 256) {
        unsigned long long k = skeys[i];
        unsigned int idx = 0xFFFFFFFFu - (unsigned int)(k & 0xFFFFFFFFull);
        size_t gi = (size_t)b * NANCH + idx;
        top_s[b * PRE_N + i] = mscores[gi];
        ((float4*)top_boxes)[b * PRE_N + i] = ((const float4*)boxes)[gi];
    }
}

// ---------------- IoU suppression bit-matrix ----------------
// grid: 8 * 125 (16 rows per block), 256 threads = 4 waves
__global__ __launch_bounds__(256) void sup_kernel(const float* __restrict__ top_boxes,
                                                  unsigned long long* __restrict__ supm) {
    int blk = blockIdx.x;
    int b = blk / 125;
    int chunk = blk % 125;
    int t = threadIdx.x;

    __shared__ float bx1[PRE_N], by1[PRE_N], bx2[PRE_N], by2[PRE_N];
    for (int i = t; i < PRE_N; i += 256) {
        float4 v = ((const float4*)top_boxes)[b * PRE_N + i];
        bx1[i] = v.x; by1[i] = v.y; bx2[i] = v.z; by2[i] = v.w;
    }
    __syncthreads();

    int wave = t >> 6, lane = t & 63;
    for (int rr = 0; rr < 4; ++rr) {
        int i = chunk * 16 + wave * 4 + rr;
        float ax1 = bx1[i], ay1 = by1[i], ax2 = bx2[i], ay2 = by2[i];
        float aarea = (ax2 - ax1) * (ay2 - ay1);
        for (int jw = 0; jw < 32; ++jw) {
            int j = jw * 64 + lane;
            bool sup = false;
            if (j > i && j < PRE_N) {
                float jx1 = bx1[j], jy1 = by1[j], jx2 = bx2[j], jy2 = by2[j];
                float ix1 = fmaxf(ax1, jx1), iy1 = fmaxf(ay1, jy1);
                float ix2 = fminf(ax2, jx2), iy2 = fminf(ay2, jy2);
                float iw = fmaxf(ix2 - ix1, 0.f);
                float ih = fmaxf(iy2 - iy1, 0.f);
                float inter = iw * ih;
                float barea = (jx2 - jx1) * (jy2 - jy1);
                float iou = inter / (aarea + barea - inter + 1e-9f);
                sup = iou > 0.7f;
            }
            unsigned long long m = __ballot(sup);
            if (lane == 0) supm[((size_t)b * PRE_N + i) * 32 + jw] = m;
        }
    }
}

// ---------------- serial NMS scan, 1 wave per batch ----------------
__global__ __launch_bounds__(64) void nms_scan_kernel(const float* __restrict__ top_s,
                                                      const unsigned long long* __restrict__ supm,
                                                      unsigned int* __restrict__ keepout) {
    int b = blockIdx.x;
    int lane = threadIdx.x;
    unsigned int keepw = 0;
    for (int q = 0; q < 32; ++q) {
        int i = lane * 32 + q;
        if (i < PRE_N && top_s[b * PRE_N + i] > 0.f) keepw |= (1u << q);
    }
    const unsigned int* sup32 = (const unsigned int*)(supm + (size_t)b * PRE_N * 32);
    for (int i = 0; i < PRE_N; ++i) {
        unsigned int wv = __shfl(keepw, i >> 5);
        if ((wv >> (i & 31)) & 1u) {
            keepw &= ~sup32[(size_t)i * 64 + lane];
        }
    }
    keepout[b * 64 + lane] = keepw;
}

// ---------------- final stable top-100 ----------------
__global__ __launch_bounds__(256) void finalize_kernel(const float* __restrict__ top_boxes,
                                                       const float* __restrict__ top_s,
                                                       const unsigned int* __restrict__ keepin,
                                                       float* __restrict__ out) {
    int b = blockIdx.x;
    int t = threadIdx.x;
    __shared__ unsigned int kw[64];
    __shared__ int wpre[65];
    if (t < 64) kw[t] = keepin[b * 64 + t];
    __syncthreads();
    if (t == 0) {
        int run = 0;
        for (int w = 0; w < 64; ++w) { wpre[w] = run; run += __popc(kw[w]); }
        wpre[64] = run;
    }
    __syncthreads();
    int total = wpre[64];
    float* out_boxes  = out;              // 8*100*4
    float* out_scores = out + NB * POST_N * 4;
    for (int i = t; i < PRE_N; i += 256) {
        unsigned int w = kw[i >> 5];
        bool kept = (w >> (i & 31)) & 1u;
        int rk = wpre[i >> 5] + __popc(w & ((1u << (i & 31)) - 1u));
        int pos = kept ? rk : total + (i - rk);
        if (pos < POST_N) {
            out_scores[b * POST_N + pos] = kept ? top_s[b * PRE_N + i] : -1.0f;
            ((float4*)out_boxes)[b * POST_N + pos] = ((const float4*)top_boxes)[b * PRE_N + i];
        }
    }
}

// ---------------- launch ----------------
extern "C" void kernel_launch(void* const* d_in, const int* in_sizes, int n_in,
                              void* d_out, int out_size, void* d_ws, size_t ws_size,
                              hipStream_t stream) {
    const float* features = (const float*)d_in[0];
    const float* W1 = (const float*)d_in[1];
    const float* b1 = (const float*)d_in[2];
    const float* W2 = (const float*)d_in[3];
    const float* b2 = (const float*)d_in[4];
    const float* W3 = (const float*)d_in[5];
    const float* b3 = (const float*)d_in[6];
    float* out = (float*)d_out;
    char* ws = (char*)d_ws;

    float* t_buf   = (float*)(ws + OFF_T);
    float* boxes   = (float*)(ws + OFF_BOXES);
    float* mscores = (float*)(ws + OFF_MS);
    unsigned long long* keys = (unsigned long long*)(ws + OFF_KEYS);
    float* top_boxes = (float*)(ws + OFF_TBOX);
    float* top_s     = (float*)(ws + OFF_TS);
    unsigned long long* supm = (unsigned long long*)(ws + OFF_SUP);
    unsigned int* keep = (unsigned int*)(ws + OFF_KEEP);

    conv_kernel<<<NB * HDIM * 4, 256, 0, stream>>>(features, W1, b1, t_buf);
    proj_decode_kernel<<<NB * HDIM, 256, 0, stream>>>(t_buf, W2, b2, W3, b3, boxes, mscores, keys);
    select_sort_kernel<<<NB, 256, 0, stream>>>(keys, boxes, mscores, top_boxes, top_s);
    sup_kernel<<<NB * 125, 256, 0, stream>>>(top_boxes, supm);
    nms_scan_kernel<<<NB, 64, 0, stream>>>(top_s, supm, keep);
    finalize_kernel<<<NB, 256, 0, stream>>>(top_boxes, top_s, keep, out);
}

// Round 2
// 5066.803 us; speedup vs baseline: 3.2941x; 3.2941x over previous
//
#include <hip/hip_runtime.h>
#include <cstdint>

#define NB 8
#define CIN 1024
#define HDIM 50
#define WDIM 50
#define COUT 512
#define NA 9
#define NANCH (HDIM*WDIM*NA)   /* 22500 */
#define PRE_N 2000
#define POST_N 100

// ---------------- workspace layout (bytes) ----------------
constexpr size_t OFF_T     = 0;                          // 8*50*50*512 f32 = 40,960,000 (layout b,h,w,co)
constexpr size_t OFF_BOXES = 40960000;                   // 8*22500*4 f32
constexpr size_t OFF_MS    = OFF_BOXES + 2880000;        // 8*22500 f32 (masked scores)
constexpr size_t OFF_KEYS  = OFF_MS + 720000;            // 8*22500 u64
constexpr size_t OFF_TBOX  = OFF_KEYS + 1440000;         // 8*2000*4 f32
constexpr size_t OFF_TS    = OFF_TBOX + 256000;          // 8*2000 f32
constexpr size_t OFF_SUP   = OFF_TS + 64000;             // 8*2000*32 u64 (suppression bits)
constexpr size_t OFF_KEEP  = OFF_SUP + 4096000;          // 8*64 u32

// ---------------- conv 3x3 + bias + relu, implicit-GEMM register-blocked ----------------
// grid: 1600 = b(8) x h2(25) x cot(8).  block tile: 2 rows x 50 px x 64 co.
// thread: colane = t&15 (4 co), pg = (t>>4)&7 (7 px, w0=pg*7), rsel = t>>7 (row).
// micro-tile 7 px x 4 co = 28 fp32 accumulators. K-chunk = 16 ci (144 k-values).
#define CK 16
__global__ __launch_bounds__(256) void conv_kernel(const float* __restrict__ f,
                                                   const float* __restrict__ W1,
                                                   const float* __restrict__ b1,
                                                   float* __restrict__ tout) {
    int blk = blockIdx.x;
    int cot = blk & 7;
    int h2  = (blk >> 3) % 25;
    int b   = blk / 200;
    int co0 = cot * 64;
    int h0  = h2 * 2;

    // sA: 16 ci x 4 rows (h0-1..h0+2) x 58 cols (col = w+1, cols 52..57 zero)
    __shared__ float sA[CK][4][58];        // 14,848 B
    // sB: transposed weights [k][co], row stride 68 floats (16B-aligned b128 reads)
    __shared__ float sB[CK * 9][68];       // 39,168 B   -> total 54,016 B: 3 blocks/CU

    int t = threadIdx.x;
    int colane = t & 15;
    int pg     = (t >> 4) & 7;
    int rsel   = t >> 7;
    int w0     = pg * 7;

    float acc[7][4];
#pragma unroll
    for (int j = 0; j < 7; ++j)
#pragma unroll
        for (int c = 0; c < 4; ++c) acc[j][c] = 0.f;

    for (int ci0 = 0; ci0 < CIN; ci0 += CK) {
        __syncthreads();
        // stage A: 16 x 4 x 58 = 3712 elements, zero-padded halo
        for (int idx = t; idx < CK * 4 * 58; idx += 256) {
            int ci  = idx / 232;
            int rem = idx - ci * 232;
            int r   = rem / 58;
            int col = rem - r * 58;      // w = col-1
            int hh  = h0 - 1 + r;
            int w   = col - 1;
            float v = 0.f;
            if (hh >= 0 && hh < HDIM && w >= 0 && w < WDIM)
                v = f[(((size_t)b * CIN + ci0 + ci) * HDIM + hh) * WDIM + w];
            sA[ci][r][col] = v;
        }
        // stage B transposed: 64 co x 144 k, global reads contiguous over k
        for (int idx = t; idx < 64 * 144; idx += 256) {
            int co = idx / 144;
            int k  = idx - co * 144;
            sB[k][co] = W1[(size_t)(co0 + co) * (CIN * 9) + ci0 * 9 + k];
        }
        __syncthreads();

#pragma unroll 2
        for (int ci = 0; ci < CK; ++ci) {
#pragma unroll
            for (int kh = 0; kh < 3; ++kh) {
                float rr[9];
#pragma unroll
                for (int x = 0; x < 9; ++x) rr[x] = sA[ci][rsel + kh][w0 + x];
#pragma unroll
                for (int kw = 0; kw < 3; ++kw) {
                    const float4 bv = *(const float4*)(&sB[ci * 9 + kh * 3 + kw][colane * 4]);
#pragma unroll
                    for (int j = 0; j < 7; ++j) {
                        float a = rr[j + kw];
                        acc[j][0] = fmaf(a, bv.x, acc[j][0]);
                        acc[j][1] = fmaf(a, bv.y, acc[j][1]);
                        acc[j][2] = fmaf(a, bv.z, acc[j][2]);
                        acc[j][3] = fmaf(a, bv.w, acc[j][3]);
                    }
                }
            }
        }
    }

    const float4 bvv = *(const float4*)&b1[co0 + colane * 4];
    int h = h0 + rsel;
    size_t rowbase = ((size_t)b * HDIM + h) * WDIM;
#pragma unroll
    for (int j = 0; j < 7; ++j) {
        int w = w0 + j;
        if (w < WDIM) {
            float4 o;
            o.x = fmaxf(acc[j][0] + bvv.x, 0.f);
            o.y = fmaxf(acc[j][1] + bvv.y, 0.f);
            o.z = fmaxf(acc[j][2] + bvv.z, 0.f);
            o.w = fmaxf(acc[j][3] + bvv.w, 0.f);
            *(float4*)&tout[(rowbase + w) * COUT + co0 + colane * 4] = o;
        }
    }
}

// ---------------- projection + decode + key build ----------------
// grid: b*50 + h ; 256 threads
__global__ __launch_bounds__(256) void proj_decode_kernel(const float* __restrict__ tin,
                                                          const float* __restrict__ W2,
                                                          const float* __restrict__ b2,
                                                          const float* __restrict__ W3,
                                                          const float* __restrict__ b3,
                                                          float* __restrict__ boxes,
                                                          float* __restrict__ mscores,
                                                          unsigned long long* __restrict__ keys) {
    int blk = blockIdx.x;           // b*50+h
    int b = blk / HDIM;
    int h = blk % HDIM;
    int t = threadIdx.x;

    __shared__ float sw[45 * 65];    // 45 rows x 64ch chunk (pad 65)
    __shared__ float tch[50 * 65];   // 50 px x 64ch chunk
    __shared__ float pout[50 * 46];  // 45 outputs per pixel (pad 46)

    float acc[9];
#pragma unroll
    for (int k = 0; k < 9; ++k) acc[k] = 0.f;

    size_t tbase = (size_t)blk * (WDIM * COUT);

    for (int c0 = 0; c0 < COUT; c0 += 64) {
        __syncthreads();
        for (int idx = t; idx < 50 * 64; idx += 256) {
            int px = idx >> 6, c = idx & 63;
            tch[px * 65 + c] = tin[tbase + (size_t)px * COUT + c0 + c];
        }
        for (int idx = t; idx < 45 * 64; idx += 256) {
            int o = idx >> 6, c = idx & 63;
            float v = (o < 36) ? W2[o * COUT + c0 + c] : W3[(o - 36) * COUT + c0 + c];
            sw[o * 65 + c] = v;
        }
        __syncthreads();
#pragma unroll
        for (int k = 0; k < 9; ++k) {
            int id = t + k * 256;
            if (id < 2250) {
                int px = id / 45;
                int o  = id - px * 45;
                float s = acc[k];
                for (int c = 0; c < 64; ++c)
                    s = fmaf(tch[px * 65 + c], sw[o * 65 + c], s);
                acc[k] = s;
            }
        }
    }
    __syncthreads();
#pragma unroll
    for (int k = 0; k < 9; ++k) {
        int id = t + k * 256;
        if (id < 2250) {
            int px = id / 45;
            int o  = id - px * 45;
            float bias = (o < 36) ? b2[o] : b3[o - 36];
            pout[px * 46 + o] = acc[k] + bias;
        }
    }
    __syncthreads();

    // decode: 50 px * 9 anchors
    const float AW[9] = {90.50966799187809f, 128.0f, 181.01933598375618f,
                         181.01933598375618f, 256.0f, 362.03867196751236f,
                         362.03867196751236f, 512.0f, 724.0773439350247f};
    const float AH[9] = {181.01933598375618f, 128.0f, 90.50966799187809f,
                         362.03867196751236f, 256.0f, 181.01933598375618f,
                         724.0773439350247f, 512.0f, 362.03867196751236f};
    const float CLIPV = 4.135166556742356f;  // log(1000/16)
    const float IMG = 1600.0f;

    for (int id = t; id < 450; id += 256) {
        int px = id / 9;
        int a  = id - px * 9;
        float tx = pout[px * 46 + a * 4 + 0];
        float ty = pout[px * 46 + a * 4 + 1];
        float tw = pout[px * 46 + a * 4 + 2];
        float th = pout[px * 46 + a * 4 + 3];
        float lg = pout[px * 46 + 36 + a];

        float s = 1.0f / (1.0f + expf(-lg));

        float cx = ((float)px + 0.5f) * 32.0f;
        float cy = ((float)h + 0.5f) * 32.0f;
        // replicate reference rounding: build corners, re-derive wa/cxa
        float x1a = cx - 0.5f * AW[a];
        float x2a = cx + 0.5f * AW[a];
        float y1a = cy - 0.5f * AH[a];
        float y2a = cy + 0.5f * AH[a];
        float waf = x2a - x1a;
        float haf = y2a - y1a;
        float cxa = x1a + 0.5f * waf;
        float cya = y1a + 0.5f * haf;

        float twc = tw < CLIPV ? tw : CLIPV;
        float thc = th < CLIPV ? th : CLIPV;
        float pxc = tx * waf + cxa;
        float pyc = ty * haf + cya;
        float pw  = expf(twc) * waf;
        float ph  = expf(thc) * haf;

        float x1 = pxc - 0.5f * pw;
        float y1 = pyc - 0.5f * ph;
        float x2 = pxc + 0.5f * pw;
        float y2 = pyc + 0.5f * ph;
        x1 = fminf(fmaxf(x1, 0.f), IMG);
        y1 = fminf(fmaxf(y1, 0.f), IMG);
        x2 = fminf(fmaxf(x2, 0.f), IMG);
        y2 = fminf(fmaxf(y2, 0.f), IMG);

        float bw = x2 - x1, bh = y2 - y1;
        bool valid = (s >= 0.1f) && (bw > 16.0f) && (bh > 16.0f);
        float m = valid ? s : -1.0f;

        int idx = (h * WDIM + px) * NA + a;
        size_t gi = (size_t)b * NANCH + idx;
        float4 bx = make_float4(x1, y1, x2, y2);
        ((float4*)boxes)[gi] = bx;
        mscores[gi] = m;
        unsigned int u = __float_as_uint(m);
        unsigned int k32 = (u & 0x80000000u) ? ~u : (u | 0x80000000u);
        keys[gi] = ((unsigned long long)k32 << 32) | (unsigned long long)(0xFFFFFFFFu - (unsigned)idx);
    }
}

// ---------------- exact stable top-2000 (radix select + bitonic) ----------------
// grid: 8 blocks (one per batch), 256 threads
__global__ __launch_bounds__(256) void select_sort_kernel(const unsigned long long* __restrict__ keys,
                                                          const float* __restrict__ boxes,
                                                          const float* __restrict__ mscores,
                                                          float* __restrict__ top_boxes,
                                                          float* __restrict__ top_s) {
    int b = blockIdx.x;
    int t = threadIdx.x;
    const unsigned long long* kb = keys + (size_t)b * NANCH;

    __shared__ unsigned int hist[2048];
    __shared__ unsigned int gs[256];
    __shared__ int s_chosen, s_rnew;
    __shared__ unsigned int s_cnt;
    __shared__ unsigned long long skeys[2048];

    const int widths[6] = {11, 11, 11, 11, 11, 9};
    unsigned long long prefix = 0;
    int bitsdone = 0;
    int r = PRE_N;

    for (int p = 0; p < 6; ++p) {
        int width = widths[p];
        int bins = 1 << width;
        int shift = 64 - bitsdone - width;
        for (int i = t; i < bins; i += 256) hist[i] = 0;
        __syncthreads();
        for (int i = t; i < NANCH; i += 256) {
            unsigned long long k = kb[i];
            bool ok = (bitsdone == 0) || ((k >> (64 - bitsdone)) == prefix);
            if (ok) atomicAdd(&hist[(unsigned)((k >> shift) & (unsigned long long)(bins - 1))], 1u);
        }
        __syncthreads();
        int G = bins / 256;
        unsigned int gsum = 0;
        for (int g = 0; g < G; ++g) gsum += hist[t * G + g];
        gs[t] = gsum;
        __syncthreads();
        if (t == 0) {
            int acc = 0, chosen = 0, rnew = 1;
            for (int g = 255; g >= 0; --g) {
                int sgv = (int)gs[g];
                if (acc + sgv >= r) {
                    for (int d = g * G + G - 1; d >= g * G; --d) {
                        int hv = (int)hist[d];
                        if (acc + hv >= r) { chosen = d; rnew = r - acc; break; }
                        acc += hv;
                    }
                    break;
                }
                acc += sgv;
            }
            s_chosen = chosen;
            s_rnew = rnew;
        }
        __syncthreads();
        prefix = (prefix << width) | (unsigned long long)s_chosen;
        bitsdone += width;
        r = s_rnew;
        __syncthreads();
    }
    unsigned long long Kst = prefix;   // exact rank-2000 key

    if (t == 0) s_cnt = 0;
    __syncthreads();
    for (int i = t; i < NANCH; i += 256) {
        unsigned long long k = kb[i];
        if (k >= Kst) {
            unsigned int p = atomicAdd(&s_cnt, 1u);
            if (p < 2048) skeys[p] = k;
        }
    }
    __syncthreads();
    unsigned int cnt = s_cnt;
    for (int i = t; i < 2048; i += 256)
        if (i >= (int)cnt) skeys[i] = 0ull;
    // bitonic sort, descending
    for (int k = 2; k <= 2048; k <<= 1) {
        for (int j = k >> 1; j > 0; j >>= 1) {
            __syncthreads();
            for (int i = t; i < 2048; i += 256) {
                int l = i ^ j;
                if (l > i) {
                    unsigned long long a = skeys[i], c = skeys[l];
                    bool up = ((i & k) == 0);
                    if (up ? (a < c) : (a > c)) { skeys[i] = c; skeys[l] = a; }
                }
            }
        }
    }
    __syncthreads();
    // gather top 2000
    for (int i = t; i < PRE_N; i += 256) {
        unsigned long long k = skeys[i];
        unsigned int idx = 0xFFFFFFFFu - (unsigned int)(k & 0xFFFFFFFFull);
        size_t gi = (size_t)b * NANCH + idx;
        top_s[b * PRE_N + i] = mscores[gi];
        ((float4*)top_boxes)[b * PRE_N + i] = ((const float4*)boxes)[gi];
    }
}

// ---------------- IoU suppression bit-matrix ----------------
// grid: 8 * 125 (16 rows per block), 256 threads = 4 waves
__global__ __launch_bounds__(256) void sup_kernel(const float* __restrict__ top_boxes,
                                                  unsigned long long* __restrict__ supm) {
    int blk = blockIdx.x;
    int b = blk / 125;
    int chunk = blk % 125;
    int t = threadIdx.x;

    __shared__ float bx1[PRE_N], by1[PRE_N], bx2[PRE_N], by2[PRE_N];
    for (int i = t; i < PRE_N; i += 256) {
        float4 v = ((const float4*)top_boxes)[b * PRE_N + i];
        bx1[i] = v.x; by1[i] = v.y; bx2[i] = v.z; by2[i] = v.w;
    }
    __syncthreads();

    int wave = t >> 6, lane = t & 63;
    for (int rr = 0; rr < 4; ++rr) {
        int i = chunk * 16 + wave * 4 + rr;
        float ax1 = bx1[i], ay1 = by1[i], ax2 = bx2[i], ay2 = by2[i];
        float aarea = (ax2 - ax1) * (ay2 - ay1);
        for (int jw = 0; jw < 32; ++jw) {
            int j = jw * 64 + lane;
            bool sup = false;
            if (j > i && j < PRE_N) {
                float jx1 = bx1[j], jy1 = by1[j], jx2 = bx2[j], jy2 = by2[j];
                float ix1 = fmaxf(ax1, jx1), iy1 = fmaxf(ay1, jy1);
                float ix2 = fminf(ax2, jx2), iy2 = fminf(ay2, jy2);
                float iw = fmaxf(ix2 - ix1, 0.f);
                float ih = fmaxf(iy2 - iy1, 0.f);
                float inter = iw * ih;
                float barea = (jx2 - jx1) * (jy2 - jy1);
                float iou = inter / (aarea + barea - inter + 1e-9f);
                sup = iou > 0.7f;
            }
            unsigned long long m = __ballot(sup);
            if (lane == 0) supm[((size_t)b * PRE_N + i) * 32 + jw] = m;
        }
    }
}

// ---------------- serial NMS scan, 1 wave per batch ----------------
__global__ __launch_bounds__(64) void nms_scan_kernel(const float* __restrict__ top_s,
                                                      const unsigned long long* __restrict__ supm,
                                                      unsigned int* __restrict__ keepout) {
    int b = blockIdx.x;
    int lane = threadIdx.x;
    unsigned int keepw = 0;
    for (int q = 0; q < 32; ++q) {
        int i = lane * 32 + q;
        if (i < PRE_N && top_s[b * PRE_N + i] > 0.f) keepw |= (1u << q);
    }
    const unsigned int* sup32 = (const unsigned int*)(supm + (size_t)b * PRE_N * 32);
    for (int i = 0; i < PRE_N; ++i) {
        unsigned int wv = __shfl(keepw, i >> 5);
        if ((wv >> (i & 31)) & 1u) {
            keepw &= ~sup32[(size_t)i * 64 + lane];
        }
    }
    keepout[b * 64 + lane] = keepw;
}

// ---------------- final stable top-100 ----------------
__global__ __launch_bounds__(256) void finalize_kernel(const float* __restrict__ top_boxes,
                                                       const float* __restrict__ top_s,
                                                       const unsigned int* __restrict__ keepin,
                                                       float* __restrict__ out) {
    int b = blockIdx.x;
    int t = threadIdx.x;
    __shared__ unsigned int kw[64];
    __shared__ int wpre[65];
    if (t < 64) kw[t] = keepin[b * 64 + t];
    __syncthreads();
    if (t == 0) {
        int run = 0;
        for (int w = 0; w < 64; ++w) { wpre[w] = run; run += __popc(kw[w]); }
        wpre[64] = run;
    }
    __syncthreads();
    int total = wpre[64];
    float* out_boxes  = out;              // 8*100*4
    float* out_scores = out + NB * POST_N * 4;
    for (int i = t; i < PRE_N; i += 256) {
        unsigned int w = kw[i >> 5];
        bool kept = (w >> (i & 31)) & 1u;
        int rk = wpre[i >> 5] + __popc(w & ((1u << (i & 31)) - 1u));
        int pos = kept ? rk : total + (i - rk);
        if (pos < POST_N) {
            out_scores[b * POST_N + pos] = kept ? top_s[b * PRE_N + i] : -1.0f;
            ((float4*)out_boxes)[b * POST_N + pos] = ((const float4*)top_boxes)[b * PRE_N + i];
        }
    }
}

// ---------------- launch ----------------
extern "C" void kernel_launch(void* const* d_in, const int* in_sizes, int n_in,
                              void* d_out, int out_size, void* d_ws, size_t ws_size,
                              hipStream_t stream) {
    const float* features = (const float*)d_in[0];
    const float* W1 = (const float*)d_in[1];
    const float* b1 = (const float*)d_in[2];
    const float* W2 = (const float*)d_in[3];
    const float* b2 = (const float*)d_in[4];
    const float* W3 = (const float*)d_in[5];
    const float* b3 = (const float*)d_in[6];
    float* out = (float*)d_out;
    char* ws = (char*)d_ws;

    float* t_buf   = (float*)(ws + OFF_T);
    float* boxes   = (float*)(ws + OFF_BOXES);
    float* mscores = (float*)(ws + OFF_MS);
    unsigned long long* keys = (unsigned long long*)(ws + OFF_KEYS);
    float* top_boxes = (float*)(ws + OFF_TBOX);
    float* top_s     = (float*)(ws + OFF_TS);
    unsigned long long* supm = (unsigned long long*)(ws + OFF_SUP);
    unsigned int* keep = (unsigned int*)(ws + OFF_KEEP);

    conv_kernel<<<NB * 25 * 8, 256, 0, stream>>>(features, W1, b1, t_buf);
    proj_decode_kernel<<<NB * HDIM, 256, 0, stream>>>(t_buf, W2, b2, W3, b3, boxes, mscores, keys);
    select_sort_kernel<<<NB, 256, 0, stream>>>(keys, boxes, mscores, top_boxes, top_s);
    sup_kernel<<<NB * 125, 256, 0, stream>>>(top_boxes, supm);
    nms_scan_kernel<<<NB, 64, 0, stream>>>(top_s, supm, keep);
    finalize_kernel<<<NB, 256, 0, stream>>>(top_boxes, top_s, keep, out);
}

// Round 3
// 1548.102 us; speedup vs baseline: 10.7814x; 3.2729x over previous
//
#include <hip/hip_runtime.h>
#include <cstdint>

#define NB 8
#define CIN 1024
#define HDIM 50
#define WDIM 50
#define COUT 512
#define NA 9
#define NANCH (HDIM*WDIM*NA)   /* 22500 */
#define PRE_N 2000
#define POST_N 100

typedef __attribute__((ext_vector_type(8))) short bf16x8;
typedef __attribute__((ext_vector_type(4))) float f32x4;
typedef __attribute__((ext_vector_type(8))) unsigned short ushort8v;

// ---------------- workspace layout (bytes) ----------------
constexpr size_t OFF_T     = 0;                          // 8*50*50*512 f32 (b,h,w,co)
constexpr size_t OFF_BOXES = 40960000;                   // 8*22500*4 f32
constexpr size_t OFF_MS    = OFF_BOXES + 2880000;        // 8*22500 f32
constexpr size_t OFF_KEYS  = OFF_MS + 720000;            // 8*22500 u64
constexpr size_t OFF_TBOX  = OFF_KEYS + 1440000;         // 8*2000*4 f32
constexpr size_t OFF_TS    = OFF_TBOX + 256000;          // 8*2000 f32
constexpr size_t OFF_SUP   = OFF_TS + 64000;             // 8*2000*32 u64
constexpr size_t OFF_KEEP  = OFF_SUP + 4096000;          // 8*64 u32
// preprocessed feature planes: [b][cic128][row52][col52][ci8] bf16 (row/col include zero halo)
constexpr size_t PPLANE    = 44310528;                   // 44,302,336 used + pad (OOB slack for last tile)
constexpr size_t OFF_PH    = 50419712;
constexpr size_t OFF_PL    = OFF_PH + PPLANE;
// preprocessed weight planes: [cot4][cic128][tap12][co128][ci8] bf16 (taps 9..11 zero)
constexpr size_t WPLANE    = 12582912;
constexpr size_t OFF_WH    = OFF_PL + PPLANE;
constexpr size_t OFF_WL    = OFF_WH + WPLANE;
// total ~164.2 MB

__device__ __forceinline__ void split2bf16(float v, unsigned short &hi, unsigned short &lo) {
    unsigned int u = __float_as_uint(v);
    unsigned int r = u + 0x7FFFu + ((u >> 16) & 1u);
    hi = (unsigned short)(r >> 16);
    float hf = __uint_as_float(((unsigned int)hi) << 16);
    float lf = v - hf;
    unsigned int u2 = __float_as_uint(lf);
    unsigned int r2 = u2 + 0x7FFFu + ((u2 >> 16) & 1u);
    lo = (unsigned short)(r2 >> 16);
}

__device__ __forceinline__ void gl_lds(const unsigned short* g, unsigned short* l) {
    __builtin_amdgcn_global_load_lds(
        (const __attribute__((address_space(1))) unsigned int*)(const void*)g,
        (__attribute__((address_space(3))) unsigned int*)(void*)l,
        16, 0, 0);
}

// ---------------- preprocess: feature -> hi/lo bf16 planes, halo baked in ----------------
// grid: 8*128*52*52/256 = 10816 blocks; thread = one (b,cic,rr,cc), handles 8 ci
__global__ __launch_bounds__(256) void prep_feat(const float* __restrict__ f,
                                                 unsigned short* __restrict__ Ph,
                                                 unsigned short* __restrict__ Pl) {
    int id = blockIdx.x * 256 + threadIdx.x;
    int cc = id % 52; int r = id / 52;
    int rr = r % 52;  r /= 52;
    int cic = r % 128; int b = r / 128;
    int h = rr - 1, w = cc - 1;
    bool inb = (h >= 0 && h < HDIM && w >= 0 && w < WDIM);
    ushort8v hv, lv;
#pragma unroll
    for (int j = 0; j < 8; ++j) {
        float v = 0.f;
        if (inb) v = f[(((size_t)b * CIN + cic * 8 + j) * HDIM + h) * WDIM + w];
        unsigned short hi, lo;
        split2bf16(v, hi, lo);
        hv[j] = hi; lv[j] = lo;
    }
    ((ushort8v*)Ph)[id] = hv;
    ((ushort8v*)Pl)[id] = lv;
}

// ---------------- preprocess: W1 -> hi/lo bf16 planes, tap-padded ----------------
// grid: 4*128*12*128/256 = 3072 blocks; thread = one (cot,cic,tap,co), 8 ci
__global__ __launch_bounds__(256) void prep_w(const float* __restrict__ W1,
                                              unsigned short* __restrict__ Wh,
                                              unsigned short* __restrict__ Wl) {
    int id = blockIdx.x * 256 + threadIdx.x;
    int co = id % 128; int r = id / 128;
    int tap = r % 12;  r /= 12;
    int cic = r % 128; int cot = r / 128;
    int cog = cot * 128 + co;
    ushort8v hv, lv;
#pragma unroll
    for (int j = 0; j < 8; ++j) {
        float v = 0.f;
        if (tap < 9) v = W1[((size_t)cog * CIN + cic * 8 + j) * 9 + tap];
        unsigned short hi, lo;
        split2bf16(v, hi, lo);
        hv[j] = hi; lv[j] = lo;
    }
    ((ushort8v*)Wh)[id] = hv;
    ((ushort8v*)Wl)[id] = lv;
}

// ---------------- conv 3x3 via split-bf16 MFMA implicit GEMM ----------------
// grid: 416 = b(8) x mt(13) x cot(4).  Block: 4 pixel-rows x 128 co.
// Wave wv owns pixel row r0+wv: 4 m-frags (w-segments) x 8 n-frags.
// MFMA 16x16x32: K=32 = 4 taps (quad q -> tap g*4+q) x 8 ci.
__global__ __launch_bounds__(256, 2) void conv_mfma(const unsigned short* __restrict__ Ph,
                                                    const unsigned short* __restrict__ Pl,
                                                    const unsigned short* __restrict__ Wh,
                                                    const unsigned short* __restrict__ Wl,
                                                    const float* __restrict__ b1,
                                                    float* __restrict__ tout) {
    __shared__ unsigned short sAh[2560];    //  5120 B: [row6][col52][ci8] + slack
    __shared__ unsigned short sAl[2560];
    __shared__ unsigned short sBh[12288];   // 24576 B: [tap12][co128][ci8]
    __shared__ unsigned short sBl[12288];

    int blk = blockIdx.x;
    int cot = blk & 3;
    int mt  = (blk >> 2) % 13;
    int b   = blk / 52;
    int r0  = mt * 4;

    int t  = threadIdx.x;
    int wv = t >> 6, ln = t & 63;
    int lm = ln & 15, q = ln >> 4;

    f32x4 acc[4][8];
#pragma unroll
    for (int j = 0; j < 4; ++j)
#pragma unroll
        for (int nf = 0; nf < 8; ++nf) acc[j][nf] = (f32x4){0.f, 0.f, 0.f, 0.f};

#pragma unroll 1
    for (int cic = 0; cic < 128; ++cic) {
        __syncthreads();
        size_t woff = (size_t)(cot * 128 + cic) * 12288;
        size_t aoff = (size_t)((b * 128 + cic) * 52 + r0) * 416;
        if (wv == 0) {
#pragma unroll
            for (int i = 0; i < 12; ++i) gl_lds(Wh + woff + i * 512 + ln * 8, &sBh[i * 512]);
#pragma unroll
            for (int i = 0; i < 5; ++i)  gl_lds(Ph + aoff + i * 512 + ln * 8, &sAh[i * 512]);
        } else if (wv == 1) {
#pragma unroll
            for (int i = 12; i < 24; ++i) gl_lds(Wh + woff + i * 512 + ln * 8, &sBh[i * 512]);
#pragma unroll
            for (int i = 0; i < 5; ++i)  gl_lds(Pl + aoff + i * 512 + ln * 8, &sAl[i * 512]);
        } else if (wv == 2) {
#pragma unroll
            for (int i = 0; i < 12; ++i) gl_lds(Wl + woff + i * 512 + ln * 8, &sBl[i * 512]);
        } else {
#pragma unroll
            for (int i = 12; i < 24; ++i) gl_lds(Wl + woff + i * 512 + ln * 8, &sBl[i * 512]);
        }
        __syncthreads();

#pragma unroll
        for (int g = 0; g < 3; ++g) {
            int tap = g * 4 + q;
            int te  = tap > 8 ? 8 : tap;      // taps 9..11 have zero weights; clamp addr only
            int kh  = te / 3;
            int kw  = te - kh * 3;
            int arow = wv + kh;               // 0..5
            bf16x8 ah[4], al[4];
#pragma unroll
            for (int j = 0; j < 4; ++j) {
                int col = j * 16 + lm + kw;
                if (col > 51) col = 51;       // pad lanes: clamp in-bounds, result unused
                int sl = (arow * 52 + col) * 8;
                ah[j] = *(const bf16x8*)&sAh[sl];
                al[j] = *(const bf16x8*)&sAl[sl];
            }
#pragma unroll
            for (int nh = 0; nh < 2; ++nh) {
                bf16x8 bh[4], bl[4];
#pragma unroll
                for (int n4 = 0; n4 < 4; ++n4) {
                    int nf = nh * 4 + n4;
                    int sl = (tap * 128 + nf * 16 + lm) * 8;
                    bh[n4] = *(const bf16x8*)&sBh[sl];
                    bl[n4] = *(const bf16x8*)&sBl[sl];
                }
#pragma unroll
                for (int j = 0; j < 4; ++j) {
#pragma unroll
                    for (int n4 = 0; n4 < 4; ++n4) {
                        int nf = nh * 4 + n4;
                        acc[j][nf] = __builtin_amdgcn_mfma_f32_16x16x32_bf16(ah[j], bh[n4], acc[j][nf], 0, 0, 0);
                        acc[j][nf] = __builtin_amdgcn_mfma_f32_16x16x32_bf16(ah[j], bl[n4], acc[j][nf], 0, 0, 0);
                        acc[j][nf] = __builtin_amdgcn_mfma_f32_16x16x32_bf16(al[j], bh[n4], acc[j][nf], 0, 0, 0);
                    }
                }
            }
        }
    }

    // epilogue: bias + relu, store valid pixels. C/D: col(n)=lane&15, row(m)=q*4+reg
    int h = r0 + wv;
    if (h >= HDIM) return;
    size_t rowb = (size_t)(b * HDIM + h) * WDIM;
#pragma unroll
    for (int nf = 0; nf < 8; ++nf) {
        float bias = b1[cot * 128 + nf * 16 + lm];
#pragma unroll
        for (int j = 0; j < 4; ++j) {
#pragma unroll
            for (int rg = 0; rg < 4; ++rg) {
                int wp = j * 16 + q * 4 + rg;
                if (wp < WDIM)
                    tout[(rowb + wp) * COUT + cot * 128 + nf * 16 + lm] =
                        fmaxf(acc[j][nf][rg] + bias, 0.f);
            }
        }
    }
}

// ---------------- projection + decode + key build ----------------
__global__ __launch_bounds__(256) void proj_decode_kernel(const float* __restrict__ tin,
                                                          const float* __restrict__ W2,
                                                          const float* __restrict__ b2,
                                                          const float* __restrict__ W3,
                                                          const float* __restrict__ b3,
                                                          float* __restrict__ boxes,
                                                          float* __restrict__ mscores,
                                                          unsigned long long* __restrict__ keys) {
    int blk = blockIdx.x;           // b*50+h
    int b = blk / HDIM;
    int h = blk % HDIM;
    int t = threadIdx.x;

    __shared__ float sw[45 * 65];
    __shared__ float tch[50 * 65];
    __shared__ float pout[50 * 46];

    float acc[9];
#pragma unroll
    for (int k = 0; k < 9; ++k) acc[k] = 0.f;

    size_t tbase = (size_t)blk * (WDIM * COUT);

    for (int c0 = 0; c0 < COUT; c0 += 64) {
        __syncthreads();
        for (int idx = t; idx < 50 * 64; idx += 256) {
            int px = idx >> 6, c = idx & 63;
            tch[px * 65 + c] = tin[tbase + (size_t)px * COUT + c0 + c];
        }
        for (int idx = t; idx < 45 * 64; idx += 256) {
            int o = idx >> 6, c = idx & 63;
            float v = (o < 36) ? W2[o * COUT + c0 + c] : W3[(o - 36) * COUT + c0 + c];
            sw[o * 65 + c] = v;
        }
        __syncthreads();
#pragma unroll
        for (int k = 0; k < 9; ++k) {
            int id = t + k * 256;
            if (id < 2250) {
                int px = id / 45;
                int o  = id - px * 45;
                float s = acc[k];
                for (int c = 0; c < 64; ++c)
                    s = fmaf(tch[px * 65 + c], sw[o * 65 + c], s);
                acc[k] = s;
            }
        }
    }
    __syncthreads();
#pragma unroll
    for (int k = 0; k < 9; ++k) {
        int id = t + k * 256;
        if (id < 2250) {
            int px = id / 45;
            int o  = id - px * 45;
            float bias = (o < 36) ? b2[o] : b3[o - 36];
            pout[px * 46 + o] = acc[k] + bias;
        }
    }
    __syncthreads();

    const float AW[9] = {90.50966799187809f, 128.0f, 181.01933598375618f,
                         181.01933598375618f, 256.0f, 362.03867196751236f,
                         362.03867196751236f, 512.0f, 724.0773439350247f};
    const float AH[9] = {181.01933598375618f, 128.0f, 90.50966799187809f,
                         362.03867196751236f, 256.0f, 181.01933598375618f,
                         724.0773439350247f, 512.0f, 362.03867196751236f};
    const float CLIPV = 4.135166556742356f;
    const float IMG = 1600.0f;

    for (int id = t; id < 450; id += 256) {
        int px = id / 9;
        int a  = id - px * 9;
        float tx = pout[px * 46 + a * 4 + 0];
        float ty = pout[px * 46 + a * 4 + 1];
        float tw = pout[px * 46 + a * 4 + 2];
        float th = pout[px * 46 + a * 4 + 3];
        float lg = pout[px * 46 + 36 + a];

        float s = 1.0f / (1.0f + expf(-lg));

        float cx = ((float)px + 0.5f) * 32.0f;
        float cy = ((float)h + 0.5f) * 32.0f;
        float x1a = cx - 0.5f * AW[a];
        float x2a = cx + 0.5f * AW[a];
        float y1a = cy - 0.5f * AH[a];
        float y2a = cy + 0.5f * AH[a];
        float waf = x2a - x1a;
        float haf = y2a - y1a;
        float cxa = x1a + 0.5f * waf;
        float cya = y1a + 0.5f * haf;

        float twc = tw < CLIPV ? tw : CLIPV;
        float thc = th < CLIPV ? th : CLIPV;
        float pxc = tx * waf + cxa;
        float pyc = ty * haf + cya;
        float pw  = expf(twc) * waf;
        float ph  = expf(thc) * haf;

        float x1 = pxc - 0.5f * pw;
        float y1 = pyc - 0.5f * ph;
        float x2 = pxc + 0.5f * pw;
        float y2 = pyc + 0.5f * ph;
        x1 = fminf(fmaxf(x1, 0.f), IMG);
        y1 = fminf(fmaxf(y1, 0.f), IMG);
        x2 = fminf(fmaxf(x2, 0.f), IMG);
        y2 = fminf(fmaxf(y2, 0.f), IMG);

        float bw = x2 - x1, bh = y2 - y1;
        bool valid = (s >= 0.1f) && (bw > 16.0f) && (bh > 16.0f);
        float m = valid ? s : -1.0f;

        int idx = (h * WDIM + px) * NA + a;
        size_t gi = (size_t)b * NANCH + idx;
        float4 bx = make_float4(x1, y1, x2, y2);
        ((float4*)boxes)[gi] = bx;
        mscores[gi] = m;
        unsigned int u = __float_as_uint(m);
        unsigned int k32 = (u & 0x80000000u) ? ~u : (u | 0x80000000u);
        keys[gi] = ((unsigned long long)k32 << 32) | (unsigned long long)(0xFFFFFFFFu - (unsigned)idx);
    }
}

// ---------------- exact stable top-2000 (radix select + bitonic) ----------------
__global__ __launch_bounds__(256) void select_sort_kernel(const unsigned long long* __restrict__ keys,
                                                          const float* __restrict__ boxes,
                                                          const float* __restrict__ mscores,
                                                          float* __restrict__ top_boxes,
                                                          float* __restrict__ top_s) {
    int b = blockIdx.x;
    int t = threadIdx.x;
    const unsigned long long* kb = keys + (size_t)b * NANCH;

    __shared__ unsigned int hist[2048];
    __shared__ unsigned int gs[256];
    __shared__ int s_chosen, s_rnew;
    __shared__ unsigned int s_cnt;
    __shared__ unsigned long long skeys[2048];

    const int widths[6] = {11, 11, 11, 11, 11, 9};
    unsigned long long prefix = 0;
    int bitsdone = 0;
    int r = PRE_N;

    for (int p = 0; p < 6; ++p) {
        int width = widths[p];
        int bins = 1 << width;
        int shift = 64 - bitsdone - width;
        for (int i = t; i < bins; i += 256) hist[i] = 0;
        __syncthreads();
        for (int i = t; i < NANCH; i += 256) {
            unsigned long long k = kb[i];
            bool ok = (bitsdone == 0) || ((k >> (64 - bitsdone)) == prefix);
            if (ok) atomicAdd(&hist[(unsigned)((k >> shift) & (unsigned long long)(bins - 1))], 1u);
        }
        __syncthreads();
        int G = bins / 256;
        unsigned int gsum = 0;
        for (int g = 0; g < G; ++g) gsum += hist[t * G + g];
        gs[t] = gsum;
        __syncthreads();
        if (t == 0) {
            int acc = 0, chosen = 0, rnew = 1;
            for (int g = 255; g >= 0; --g) {
                int sgv = (int)gs[g];
                if (acc + sgv >= r) {
                    for (int d = g * G + G - 1; d >= g * G; --d) {
                        int hv = (int)hist[d];
                        if (acc + hv >= r) { chosen = d; rnew = r - acc; break; }
                        acc += hv;
                    }
                    break;
                }
                acc += sgv;
            }
            s_chosen = chosen;
            s_rnew = rnew;
        }
        __syncthreads();
        prefix = (prefix << width) | (unsigned long long)s_chosen;
        bitsdone += width;
        r = s_rnew;
        __syncthreads();
    }
    unsigned long long Kst = prefix;

    if (t == 0) s_cnt = 0;
    __syncthreads();
    for (int i = t; i < NANCH; i += 256) {
        unsigned long long k = kb[i];
        if (k >= Kst) {
            unsigned int p = atomicAdd(&s_cnt, 1u);
            if (p < 2048) skeys[p] = k;
        }
    }
    __syncthreads();
    unsigned int cnt = s_cnt;
    for (int i = t; i < 2048; i += 256)
        if (i >= (int)cnt) skeys[i] = 0ull;
    for (int k = 2; k <= 2048; k <<= 1) {
        for (int j = k >> 1; j > 0; j >>= 1) {
            __syncthreads();
            for (int i = t; i < 2048; i += 256) {
                int l = i ^ j;
                if (l > i) {
                    unsigned long long a = skeys[i], c = skeys[l];
                    bool up = ((i & k) == 0);
                    if (up ? (a < c) : (a > c)) { skeys[i] = c; skeys[l] = a; }
                }
            }
        }
    }
    __syncthreads();
    for (int i = t; i < PRE_N; i += 256) {
        unsigned long long k = skeys[i];
        unsigned int idx = 0xFFFFFFFFu - (unsigned int)(k & 0xFFFFFFFFull);
        size_t gi = (size_t)b * NANCH + idx;
        top_s[b * PRE_N + i] = mscores[gi];
        ((float4*)top_boxes)[b * PRE_N + i] = ((const float4*)boxes)[gi];
    }
}

// ---------------- IoU suppression bit-matrix ----------------
__global__ __launch_bounds__(256) void sup_kernel(const float* __restrict__ top_boxes,
                                                  unsigned long long* __restrict__ supm) {
    int blk = blockIdx.x;
    int b = blk / 125;
    int chunk = blk % 125;
    int t = threadIdx.x;

    __shared__ float bx1[PRE_N], by1[PRE_N], bx2[PRE_N], by2[PRE_N];
    for (int i = t; i < PRE_N; i += 256) {
        float4 v = ((const float4*)top_boxes)[b * PRE_N + i];
        bx1[i] = v.x; by1[i] = v.y; bx2[i] = v.z; by2[i] = v.w;
    }
    __syncthreads();

    int wave = t >> 6, lane = t & 63;
    for (int rr = 0; rr < 4; ++rr) {
        int i = chunk * 16 + wave * 4 + rr;
        float ax1 = bx1[i], ay1 = by1[i], ax2 = bx2[i], ay2 = by2[i];
        float aarea = (ax2 - ax1) * (ay2 - ay1);
        for (int jw = 0; jw < 32; ++jw) {
            int j = jw * 64 + lane;
            bool sup = false;
            if (j > i && j < PRE_N) {
                float jx1 = bx1[j], jy1 = by1[j], jx2 = bx2[j], jy2 = by2[j];
                float ix1 = fmaxf(ax1, jx1), iy1 = fmaxf(ay1, jy1);
                float ix2 = fminf(ax2, jx2), iy2 = fminf(ay2, jy2);
                float iw = fmaxf(ix2 - ix1, 0.f);
                float ih = fmaxf(iy2 - iy1, 0.f);
                float inter = iw * ih;
                float barea = (jx2 - jx1) * (jy2 - jy1);
                float iou = inter / (aarea + barea - inter + 1e-9f);
                sup = iou > 0.7f;
            }
            unsigned long long m = __ballot(sup);
            if (lane == 0) supm[((size_t)b * PRE_N + i) * 32 + jw] = m;
        }
    }
}

// ---------------- serial NMS scan, 1 wave per batch ----------------
__global__ __launch_bounds__(64) void nms_scan_kernel(const float* __restrict__ top_s,
                                                      const unsigned long long* __restrict__ supm,
                                                      unsigned int* __restrict__ keepout) {
    int b = blockIdx.x;
    int lane = threadIdx.x;
    unsigned int keepw = 0;
    for (int q = 0; q < 32; ++q) {
        int i = lane * 32 + q;
        if (i < PRE_N && top_s[b * PRE_N + i] > 0.f) keepw |= (1u << q);
    }
    const unsigned int* sup32 = (const unsigned int*)(supm + (size_t)b * PRE_N * 32);
    for (int i = 0; i < PRE_N; ++i) {
        unsigned int wv = __shfl(keepw, i >> 5);
        if ((wv >> (i & 31)) & 1u) {
            keepw &= ~sup32[(size_t)i * 64 + lane];
        }
    }
    keepout[b * 64 + lane] = keepw;
}

// ---------------- final stable top-100 ----------------
__global__ __launch_bounds__(256) void finalize_kernel(const float* __restrict__ top_boxes,
                                                       const float* __restrict__ top_s,
                                                       const unsigned int* __restrict__ keepin,
                                                       float* __restrict__ out) {
    int b = blockIdx.x;
    int t = threadIdx.x;
    __shared__ unsigned int kw[64];
    __shared__ int wpre[65];
    if (t < 64) kw[t] = keepin[b * 64 + t];
    __syncthreads();
    if (t == 0) {
        int run = 0;
        for (int w = 0; w < 64; ++w) { wpre[w] = run; run += __popc(kw[w]); }
        wpre[64] = run;
    }
    __syncthreads();
    int total = wpre[64];
    float* out_boxes  = out;
    float* out_scores = out + NB * POST_N * 4;
    for (int i = t; i < PRE_N; i += 256) {
        unsigned int w = kw[i >> 5];
        bool kept = (w >> (i & 31)) & 1u;
        int rk = wpre[i >> 5] + __popc(w & ((1u << (i & 31)) - 1u));
        int pos = kept ? rk : total + (i - rk);
        if (pos < POST_N) {
            out_scores[b * POST_N + pos] = kept ? top_s[b * PRE_N + i] : -1.0f;
            ((float4*)out_boxes)[b * POST_N + pos] = ((const float4*)top_boxes)[b * PRE_N + i];
        }
    }
}

// ---------------- launch ----------------
extern "C" void kernel_launch(void* const* d_in, const int* in_sizes, int n_in,
                              void* d_out, int out_size, void* d_ws, size_t ws_size,
                              hipStream_t stream) {
    const float* features = (const float*)d_in[0];
    const float* W1 = (const float*)d_in[1];
    const float* b1 = (const float*)d_in[2];
    const float* W2 = (const float*)d_in[3];
    const float* b2 = (const float*)d_in[4];
    const float* W3 = (const float*)d_in[5];
    const float* b3 = (const float*)d_in[6];
    float* out = (float*)d_out;
    char* ws = (char*)d_ws;

    float* t_buf   = (float*)(ws + OFF_T);
    float* boxes   = (float*)(ws + OFF_BOXES);
    float* mscores = (float*)(ws + OFF_MS);
    unsigned long long* keys = (unsigned long long*)(ws + OFF_KEYS);
    float* top_boxes = (float*)(ws + OFF_TBOX);
    float* top_s     = (float*)(ws + OFF_TS);
    unsigned long long* supm = (unsigned long long*)(ws + OFF_SUP);
    unsigned int* keep = (unsigned int*)(ws + OFF_KEEP);
    unsigned short* Ph = (unsigned short*)(ws + OFF_PH);
    unsigned short* Pl = (unsigned short*)(ws + OFF_PL);
    unsigned short* Wh = (unsigned short*)(ws + OFF_WH);
    unsigned short* Wl = (unsigned short*)(ws + OFF_WL);

    prep_feat<<<10816, 256, 0, stream>>>(features, Ph, Pl);
    prep_w<<<3072, 256, 0, stream>>>(W1, Wh, Wl);
    conv_mfma<<<416, 256, 0, stream>>>(Ph, Pl, Wh, Wl, b1, t_buf);
    proj_decode_kernel<<<NB * HDIM, 256, 0, stream>>>(t_buf, W2, b2, W3, b3, boxes, mscores, keys);
    select_sort_kernel<<<NB, 256, 0, stream>>>(keys, boxes, mscores, top_boxes, top_s);
    sup_kernel<<<NB * 125, 256, 0, stream>>>(top_boxes, supm);
    nms_scan_kernel<<<NB, 64, 0, stream>>>(top_s, supm, keep);
    finalize_kernel<<<NB, 256, 0, stream>>>(top_boxes, top_s, keep, out);
}

// Round 4
// 1377.297 us; speedup vs baseline: 12.1184x; 1.1240x over previous
//
#include <hip/hip_runtime.h>
#include <cstdint>

#define NB 8
#define CIN 1024
#define HDIM 50
#define WDIM 50
#define COUT 512
#define NA 9
#define NANCH (HDIM*WDIM*NA)   /* 22500 */
#define PRE_N 2000
#define POST_N 100

typedef __attribute__((ext_vector_type(8))) short bf16x8;
typedef __attribute__((ext_vector_type(4))) float f32x4;
typedef __attribute__((ext_vector_type(16))) float f32x16;
typedef __attribute__((ext_vector_type(8))) unsigned short ushort8v;

// ---------------- workspace layout (bytes) ----------------
constexpr size_t OFF_T     = 0;                          // 20000*512 f32 = 40,960,000 ([px][co])
constexpr size_t OFF_BOXES = 40960000;                   // 8*22500*4 f32
constexpr size_t OFF_MS    = OFF_BOXES + 2880000;        // 8*22500 f32
constexpr size_t OFF_KEYS  = OFF_MS + 720000;            // 8*22500 u64
constexpr size_t OFF_TBOX  = OFF_KEYS + 1440000;         // 8*2000*4 f32
constexpr size_t OFF_TS    = OFF_TBOX + 256000;          // 8*2000 f32
constexpr size_t OFF_SUP   = OFF_TS + 64000;             // 8*2000*32 u64
constexpr size_t OFF_KEEP  = OFF_SUP + 4096000;          // 8*64 u32
// feature planes: [b8][cic64][rr52][cc52][ci16] bf16 (rr/cc include zero halo)
constexpr size_t PPLANE    = 44318720;                   // 44,302,336 used + 16KB slack
constexpr size_t OFF_PH    = 50419712;
constexpr size_t OFF_PL    = OFF_PH + PPLANE;
// weight planes: [cot8][cic64][tap9][co64][ci16] bf16
constexpr size_t WPLANE    = 9437184;
constexpr size_t OFF_WH    = OFF_PL + PPLANE;
constexpr size_t OFF_WL    = OFF_WH + WPLANE;
// end ~158 MB

__device__ __forceinline__ void split2bf16(float v, unsigned short &hi, unsigned short &lo) {
    unsigned int u = __float_as_uint(v);
    unsigned int r = u + 0x7FFFu + ((u >> 16) & 1u);
    hi = (unsigned short)(r >> 16);
    float hf = __uint_as_float(((unsigned int)hi) << 16);
    float lf = v - hf;
    unsigned int u2 = __float_as_uint(lf);
    unsigned int r2 = u2 + 0x7FFFu + ((u2 >> 16) & 1u);
    lo = (unsigned short)(r2 >> 16);
}

__device__ __forceinline__ void gl_lds(const unsigned short* g, unsigned short* l) {
    __builtin_amdgcn_global_load_lds(
        (const __attribute__((address_space(1))) unsigned int*)(const void*)g,
        (__attribute__((address_space(3))) unsigned int*)(void*)l,
        16, 0, 0);
}

// ---------------- preprocess: feature -> hi/lo bf16 planes, halo baked in ----------------
// thread = one (b,cic,rr,cc), handles 16 ci. grid: 8*64*52*52/256 = 5408
__global__ __launch_bounds__(256) void prep_feat(const float* __restrict__ f,
                                                 unsigned short* __restrict__ Ph,
                                                 unsigned short* __restrict__ Pl) {
    int id = blockIdx.x * 256 + threadIdx.x;
    int cc = id % 52; int r = id / 52;
    int rr = r % 52;  r /= 52;
    int cic = r % 64; int b = r / 64;
    int h = rr - 1, w = cc - 1;
    bool inb = (h >= 0 && h < HDIM && w >= 0 && w < WDIM);
    ushort8v hv0, lv0, hv1, lv1;
#pragma unroll
    for (int j = 0; j < 16; ++j) {
        float v = 0.f;
        if (inb) v = f[(((size_t)b * CIN + cic * 16 + j) * HDIM + h) * WDIM + w];
        unsigned short hi, lo;
        split2bf16(v, hi, lo);
        if (j < 8) { hv0[j] = hi; lv0[j] = lo; }
        else       { hv1[j - 8] = hi; lv1[j - 8] = lo; }
    }
    size_t base = (size_t)id * 16;
    *(ushort8v*)&Ph[base]     = hv0;
    *(ushort8v*)&Ph[base + 8] = hv1;
    *(ushort8v*)&Pl[base]     = lv0;
    *(ushort8v*)&Pl[base + 8] = lv1;
}

// ---------------- preprocess: W1 -> hi/lo bf16 planes [cot][cic][tap][co][ci16] ----------------
// thread = one (cot,cic,co), handles 9 taps x 16 ci. grid: 8*64*64/256 = 128
__global__ __launch_bounds__(256) void prep_w(const float* __restrict__ W1,
                                              unsigned short* __restrict__ Wh,
                                              unsigned short* __restrict__ Wl) {
    int id = blockIdx.x * 256 + threadIdx.x;
    int co = id % 64; int r = id / 64;
    int cic = r % 64; int cot = r / 64;
    int cog = cot * 64 + co;
    const float* src = W1 + ((size_t)cog * CIN + cic * 16) * 9;   // 144 consecutive floats
    float v[144];
#pragma unroll
    for (int i = 0; i < 36; ++i) {
        float4 x = ((const float4*)src)[i];
        v[i * 4 + 0] = x.x; v[i * 4 + 1] = x.y; v[i * 4 + 2] = x.z; v[i * 4 + 3] = x.w;
    }
#pragma unroll
    for (int tap = 0; tap < 9; ++tap) {
        ushort8v hv0, lv0, hv1, lv1;
#pragma unroll
        for (int j = 0; j < 16; ++j) {
            unsigned short hi, lo;
            split2bf16(v[j * 9 + tap], hi, lo);
            if (j < 8) { hv0[j] = hi; lv0[j] = lo; }
            else       { hv1[j - 8] = hi; lv1[j - 8] = lo; }
        }
        size_t base = ((((size_t)(cot * 64 + cic)) * 9 + tap) * 64 + co) * 16;
        *(ushort8v*)&Wh[base]     = hv0;
        *(ushort8v*)&Wh[base + 8] = hv1;
        *(ushort8v*)&Wl[base]     = lv0;
        *(ushort8v*)&Wl[base + 8] = lv1;
    }
}

// ---------------- conv 3x3 via split-bf16 MFMA 32x32x16, no tap padding ----------------
// grid: 832 = b(8) x mt(13) x cot(8). Block: 4 rows x 64 cols(M) x 64 co(N).
// Wave wv owns row h = mt*4+wv: 2 m-frags(32 px) x 2 n-frags(32 co).
// K per MFMA = 16 ci of one tap; 9 taps x 64 cic-chunks = K 9216 exact.
__global__ __launch_bounds__(256, 2) void conv_mfma(const unsigned short* __restrict__ FPh,
                                                    const unsigned short* __restrict__ FPl,
                                                    const unsigned short* __restrict__ WPh,
                                                    const unsigned short* __restrict__ WPl,
                                                    const float* __restrict__ b1,
                                                    float* __restrict__ tout) {
    __shared__ unsigned short sAh[5120], sAl[5120];   // [row6][cc52][ci16] + slack
    __shared__ unsigned short sBh[9216], sBl[9216];   // [tap9][co64][ci16]

    int blk = blockIdx.x;
    int cot = blk & 7;
    int mt  = (blk >> 3) % 13;
    int b   = blk / 104;
    int co0 = cot * 64;
    int r0  = mt * 4;

    int t = threadIdx.x, wv = t >> 6, ln = t & 63;
    int lm = ln & 31, lk = ln >> 5;

    f32x16 acc[2][2];
#pragma unroll
    for (int jm = 0; jm < 2; ++jm)
#pragma unroll
        for (int jn = 0; jn < 2; ++jn)
#pragma unroll
            for (int rg = 0; rg < 16; ++rg) acc[jm][jn][rg] = 0.f;

#pragma unroll 1
    for (int cic = 0; cic < 64; ++cic) {
        __syncthreads();
        const unsigned short* wH = WPh + (size_t)(cot * 64 + cic) * 9216;
        const unsigned short* wL = WPl + (size_t)(cot * 64 + cic) * 9216;
        const unsigned short* aH = FPh + (size_t)((b * 64 + cic) * 52 + r0) * 832;
        const unsigned short* aL = FPl + (size_t)((b * 64 + cic) * 52 + r0) * 832;
        if (wv == 0) {
#pragma unroll
            for (int s = 0; s < 14; ++s) gl_lds(wH + s * 512 + ln * 8, &sBh[s * 512]);
        } else if (wv == 1) {
#pragma unroll
            for (int s = 14; s < 18; ++s) gl_lds(wH + s * 512 + ln * 8, &sBh[s * 512]);
#pragma unroll
            for (int s = 0; s < 10; ++s) gl_lds(wL + s * 512 + ln * 8, &sBl[s * 512]);
        } else if (wv == 2) {
#pragma unroll
            for (int s = 10; s < 18; ++s) gl_lds(wL + s * 512 + ln * 8, &sBl[s * 512]);
#pragma unroll
            for (int s = 0; s < 6; ++s)  gl_lds(aH + s * 512 + ln * 8, &sAh[s * 512]);
        } else {
#pragma unroll
            for (int s = 6; s < 10; ++s) gl_lds(aH + s * 512 + ln * 8, &sAh[s * 512]);
#pragma unroll
            for (int s = 0; s < 10; ++s) gl_lds(aL + s * 512 + ln * 8, &sAl[s * 512]);
        }
        __syncthreads();

#pragma unroll
        for (int tap = 0; tap < 9; ++tap) {
            const int kh = tap / 3, kw = tap % 3;
            int arow = wv + kh;
            bf16x8 a[2][2], bb[2][2];
#pragma unroll
            for (int jm = 0; jm < 2; ++jm) {
                int cc = jm * 32 + lm + kw;
                if (cc > 51) cc = 51;                  // pad lanes: clamp, result unused
                int ad = (arow * 52 + cc) * 16 + lk * 8;
                a[jm][0] = *(const bf16x8*)&sAh[ad];
                a[jm][1] = *(const bf16x8*)&sAl[ad];
            }
#pragma unroll
            for (int jn = 0; jn < 2; ++jn) {
                int bd = (tap * 64 + jn * 32 + lm) * 16 + lk * 8;
                bb[jn][0] = *(const bf16x8*)&sBh[bd];
                bb[jn][1] = *(const bf16x8*)&sBl[bd];
            }
#pragma unroll
            for (int jm = 0; jm < 2; ++jm)
#pragma unroll
                for (int jn = 0; jn < 2; ++jn) {
                    acc[jm][jn] = __builtin_amdgcn_mfma_f32_32x32x16_bf16(a[jm][0], bb[jn][0], acc[jm][jn], 0, 0, 0);
                    acc[jm][jn] = __builtin_amdgcn_mfma_f32_32x32x16_bf16(a[jm][0], bb[jn][1], acc[jm][jn], 0, 0, 0);
                    acc[jm][jn] = __builtin_amdgcn_mfma_f32_32x32x16_bf16(a[jm][1], bb[jn][0], acc[jm][jn], 0, 0, 0);
                }
        }
    }

    // epilogue. C/D 32x32: col(n)=lane&31, row(m)=(reg&3)+8*(reg>>2)+4*(lane>>5)
    int h = r0 + wv;
    if (h >= HDIM) return;
    size_t rowb = (size_t)(b * HDIM + h) * WDIM;
#pragma unroll
    for (int jn = 0; jn < 2; ++jn) {
        float bv = b1[co0 + jn * 32 + lm];
#pragma unroll
        for (int jm = 0; jm < 2; ++jm) {
#pragma unroll
            for (int rg = 0; rg < 16; ++rg) {
                int w = jm * 32 + (rg & 3) + 8 * (rg >> 2) + 4 * lk;
                if (w < WDIM)
                    tout[(rowb + w) * COUT + co0 + jn * 32 + lm] =
                        fmaxf(acc[jm][jn][rg] + bv, 0.f);
            }
        }
    }
}

// ---------------- projection (MFMA) + decode + key build, fused ----------------
// grid: 157 blocks x 256 thr. Block: 128 px(M) x 48 o(N, 45 used), K=512.
__global__ __launch_bounds__(256) void proj_decode_mfma(const float* __restrict__ tin,
                                                        const float* __restrict__ W2,
                                                        const float* __restrict__ b2,
                                                        const float* __restrict__ W3,
                                                        const float* __restrict__ b3,
                                                        float* __restrict__ boxes,
                                                        float* __restrict__ mscores,
                                                        unsigned long long* __restrict__ keys) {
    __shared__ unsigned short sTh[4096], sTl[4096];   // A frag-order [mf8][cig4][pxl16][8]
    __shared__ unsigned short sWh[1536], sWl[1536];   // B frag-order [nf3][cig4][ol16][8]
    __shared__ float pout[128 * 46];

    int blk = blockIdx.x;
    int px0 = blk * 128;
    int t = threadIdx.x, wv = t >> 6, ln = t & 63;
    int lm = ln & 15, q = ln >> 4;

    f32x4 acc[2][3];
#pragma unroll
    for (int jm = 0; jm < 2; ++jm)
#pragma unroll
        for (int nf = 0; nf < 3; ++nf) acc[jm][nf] = (f32x4){0.f, 0.f, 0.f, 0.f};

#pragma unroll 1
    for (int c0 = 0; c0 < 512; c0 += 32) {
        __syncthreads();
        {   // A staging: thread -> (px = t>>1, half = t&1) covering 16 ci
            int px = t >> 1, half = t & 1;
            int pxg = px0 + px; if (pxg > 19999) pxg = 19999;
            const float* src = tin + (size_t)pxg * 512 + c0 + half * 16;
            float vv[16];
#pragma unroll
            for (int i = 0; i < 4; ++i) {
                float4 x = ((const float4*)src)[i];
                vv[i * 4 + 0] = x.x; vv[i * 4 + 1] = x.y; vv[i * 4 + 2] = x.z; vv[i * 4 + 3] = x.w;
            }
            int mf = px >> 4, pxl = px & 15;
#pragma unroll
            for (int g = 0; g < 2; ++g) {
                ushort8v hv, lv;
#pragma unroll
                for (int j = 0; j < 8; ++j) {
                    unsigned short hi, lo;
                    split2bf16(vv[g * 8 + j], hi, lo);
                    hv[j] = hi; lv[j] = lo;
                }
                int cig = half * 2 + g;
                int ad = ((mf * 4 + cig) * 16 + pxl) * 8;
                *(ushort8v*)&sTh[ad] = hv;
                *(ushort8v*)&sTl[ad] = lv;
            }
        }
        for (int idx = t; idx < 1536; idx += 256) {   // B staging
            int o = idx >> 5, ci = idx & 31;
            float v = 0.f;
            if (o < 36) v = W2[o * 512 + c0 + ci];
            else if (o < 45) v = W3[(o - 36) * 512 + c0 + ci];
            unsigned short hi, lo;
            split2bf16(v, hi, lo);
            int ad = (((o >> 4) * 4 + (ci >> 3)) * 16 + (o & 15)) * 8 + (ci & 7);
            sWh[ad] = hi; sWl[ad] = lo;
        }
        __syncthreads();

        bf16x8 a[2][2], bb[3][2];
#pragma unroll
        for (int jm = 0; jm < 2; ++jm) {
            int mf = wv * 2 + jm;
            int ad = ((mf * 4 + q) * 16 + lm) * 8;
            a[jm][0] = *(const bf16x8*)&sTh[ad];
            a[jm][1] = *(const bf16x8*)&sTl[ad];
        }
#pragma unroll
        for (int nf = 0; nf < 3; ++nf) {
            int ad = ((nf * 4 + q) * 16 + lm) * 8;
            bb[nf][0] = *(const bf16x8*)&sWh[ad];
            bb[nf][1] = *(const bf16x8*)&sWl[ad];
        }
#pragma unroll
        for (int jm = 0; jm < 2; ++jm)
#pragma unroll
            for (int nf = 0; nf < 3; ++nf) {
                acc[jm][nf] = __builtin_amdgcn_mfma_f32_16x16x32_bf16(a[jm][0], bb[nf][0], acc[jm][nf], 0, 0, 0);
                acc[jm][nf] = __builtin_amdgcn_mfma_f32_16x16x32_bf16(a[jm][0], bb[nf][1], acc[jm][nf], 0, 0, 0);
                acc[jm][nf] = __builtin_amdgcn_mfma_f32_16x16x32_bf16(a[jm][1], bb[nf][0], acc[jm][nf], 0, 0, 0);
            }
    }
    __syncthreads();
    // C -> pout. C/D 16x16: col=lane&15 (o), row=q*4+reg (px within frag)
#pragma unroll
    for (int jm = 0; jm < 2; ++jm)
#pragma unroll
        for (int nf = 0; nf < 3; ++nf) {
            int o = nf * 16 + lm;
            if (o < 45) {
                float bias = (o < 36) ? b2[o] : b3[o - 36];
#pragma unroll
                for (int rg = 0; rg < 4; ++rg) {
                    int pxl = (wv * 2 + jm) * 16 + q * 4 + rg;
                    pout[pxl * 46 + o] = acc[jm][nf][rg] + bias;
                }
            }
        }
    __syncthreads();

    const float AW[9] = {90.50966799187809f, 128.0f, 181.01933598375618f,
                         181.01933598375618f, 256.0f, 362.03867196751236f,
                         362.03867196751236f, 512.0f, 724.0773439350247f};
    const float AH[9] = {181.01933598375618f, 128.0f, 90.50966799187809f,
                         362.03867196751236f, 256.0f, 181.01933598375618f,
                         724.0773439350247f, 512.0f, 362.03867196751236f};
    const float CLIPV = 4.135166556742356f;
    const float IMG = 1600.0f;

    for (int it = t; it < 128 * 9; it += 256) {
        int pxl = it / 9, a = it - pxl * 9;
        int pxg = px0 + pxl;
        if (pxg >= 20000) continue;
        int b = pxg / 2500, rem = pxg % 2500;
        int h = rem / 50, w = rem % 50;

        float tx = pout[pxl * 46 + a * 4 + 0];
        float ty = pout[pxl * 46 + a * 4 + 1];
        float tw = pout[pxl * 46 + a * 4 + 2];
        float th = pout[pxl * 46 + a * 4 + 3];
        float lg = pout[pxl * 46 + 36 + a];

        float s = 1.0f / (1.0f + expf(-lg));

        float cx = ((float)w + 0.5f) * 32.0f;
        float cy = ((float)h + 0.5f) * 32.0f;
        float x1a = cx - 0.5f * AW[a];
        float x2a = cx + 0.5f * AW[a];
        float y1a = cy - 0.5f * AH[a];
        float y2a = cy + 0.5f * AH[a];
        float waf = x2a - x1a;
        float haf = y2a - y1a;
        float cxa = x1a + 0.5f * waf;
        float cya = y1a + 0.5f * haf;

        float twc = tw < CLIPV ? tw : CLIPV;
        float thc = th < CLIPV ? th : CLIPV;
        float pxc = tx * waf + cxa;
        float pyc = ty * haf + cya;
        float pw  = expf(twc) * waf;
        float ph  = expf(thc) * haf;

        float x1 = pxc - 0.5f * pw;
        float y1 = pyc - 0.5f * ph;
        float x2 = pxc + 0.5f * pw;
        float y2 = pyc + 0.5f * ph;
        x1 = fminf(fmaxf(x1, 0.f), IMG);
        y1 = fminf(fmaxf(y1, 0.f), IMG);
        x2 = fminf(fmaxf(x2, 0.f), IMG);
        y2 = fminf(fmaxf(y2, 0.f), IMG);

        float bw = x2 - x1, bh = y2 - y1;
        bool valid = (s >= 0.1f) && (bw > 16.0f) && (bh > 16.0f);
        float m = valid ? s : -1.0f;

        int idx = (h * WDIM + w) * NA + a;
        size_t gi = (size_t)b * NANCH + idx;
        ((float4*)boxes)[gi] = make_float4(x1, y1, x2, y2);
        mscores[gi] = m;
        unsigned int u = __float_as_uint(m);
        unsigned int k32 = (u & 0x80000000u) ? ~u : (u | 0x80000000u);
        keys[gi] = ((unsigned long long)k32 << 32) | (unsigned long long)(0xFFFFFFFFu - (unsigned)idx);
    }
}

// ---------------- exact stable top-2000 (radix select + bitonic) ----------------
__global__ __launch_bounds__(256) void select_sort_kernel(const unsigned long long* __restrict__ keys,
                                                          const float* __restrict__ boxes,
                                                          const float* __restrict__ mscores,
                                                          float* __restrict__ top_boxes,
                                                          float* __restrict__ top_s) {
    int b = blockIdx.x;
    int t = threadIdx.x;
    const unsigned long long* kb = keys + (size_t)b * NANCH;

    __shared__ unsigned int hist[2048];
    __shared__ unsigned int gs[256];
    __shared__ int s_chosen, s_rnew;
    __shared__ unsigned int s_cnt;
    __shared__ unsigned long long skeys[2048];

    const int widths[6] = {11, 11, 11, 11, 11, 9};
    unsigned long long prefix = 0;
    int bitsdone = 0;
    int r = PRE_N;

    for (int p = 0; p < 6; ++p) {
        int width = widths[p];
        int bins = 1 << width;
        int shift = 64 - bitsdone - width;
        for (int i = t; i < bins; i += 256) hist[i] = 0;
        __syncthreads();
        for (int i = t; i < NANCH; i += 256) {
            unsigned long long k = kb[i];
            bool ok = (bitsdone == 0) || ((k >> (64 - bitsdone)) == prefix);
            if (ok) atomicAdd(&hist[(unsigned)((k >> shift) & (unsigned long long)(bins - 1))], 1u);
        }
        __syncthreads();
        int G = bins / 256;
        unsigned int gsum = 0;
        for (int g = 0; g < G; ++g) gsum += hist[t * G + g];
        gs[t] = gsum;
        __syncthreads();
        if (t == 0) {
            int acc = 0, chosen = 0, rnew = 1;
            for (int g = 255; g >= 0; --g) {
                int sgv = (int)gs[g];
                if (acc + sgv >= r) {
                    for (int d = g * G + G - 1; d >= g * G; --d) {
                        int hv = (int)hist[d];
                        if (acc + hv >= r) { chosen = d; rnew = r - acc; break; }
                        acc += hv;
                    }
                    break;
                }
                acc += sgv;
            }
            s_chosen = chosen;
            s_rnew = rnew;
        }
        __syncthreads();
        prefix = (prefix << width) | (unsigned long long)s_chosen;
        bitsdone += width;
        r = s_rnew;
        __syncthreads();
    }
    unsigned long long Kst = prefix;

    if (t == 0) s_cnt = 0;
    __syncthreads();
    for (int i = t; i < NANCH; i += 256) {
        unsigned long long k = kb[i];
        if (k >= Kst) {
            unsigned int p = atomicAdd(&s_cnt, 1u);
            if (p < 2048) skeys[p] = k;
        }
    }
    __syncthreads();
    unsigned int cnt = s_cnt;
    for (int i = t; i < 2048; i += 256)
        if (i >= (int)cnt) skeys[i] = 0ull;
    for (int k = 2; k <= 2048; k <<= 1) {
        for (int j = k >> 1; j > 0; j >>= 1) {
            __syncthreads();
            for (int i = t; i < 2048; i += 256) {
                int l = i ^ j;
                if (l > i) {
                    unsigned long long a = skeys[i], c = skeys[l];
                    bool up = ((i & k) == 0);
                    if (up ? (a < c) : (a > c)) { skeys[i] = c; skeys[l] = a; }
                }
            }
        }
    }
    __syncthreads();
    for (int i = t; i < PRE_N; i += 256) {
        unsigned long long k = skeys[i];
        unsigned int idx = 0xFFFFFFFFu - (unsigned int)(k & 0xFFFFFFFFull);
        size_t gi = (size_t)b * NANCH + idx;
        top_s[b * PRE_N + i] = mscores[gi];
        ((float4*)top_boxes)[b * PRE_N + i] = ((const float4*)boxes)[gi];
    }
}

// ---------------- IoU suppression bit-matrix ----------------
__global__ __launch_bounds__(256) void sup_kernel(const float* __restrict__ top_boxes,
                                                  unsigned long long* __restrict__ supm) {
    int blk = blockIdx.x;
    int b = blk / 125;
    int chunk = blk % 125;
    int t = threadIdx.x;

    __shared__ float bx1[PRE_N], by1[PRE_N], bx2[PRE_N], by2[PRE_N];
    for (int i = t; i < PRE_N; i += 256) {
        float4 v = ((const float4*)top_boxes)[b * PRE_N + i];
        bx1[i] = v.x; by1[i] = v.y; bx2[i] = v.z; by2[i] = v.w;
    }
    __syncthreads();

    int wave = t >> 6, lane = t & 63;
    for (int rr = 0; rr < 4; ++rr) {
        int i = chunk * 16 + wave * 4 + rr;
        float ax1 = bx1[i], ay1 = by1[i], ax2 = bx2[i], ay2 = by2[i];
        float aarea = (ax2 - ax1) * (ay2 - ay1);
        for (int jw = 0; jw < 32; ++jw) {
            int j = jw * 64 + lane;
            bool sup = false;
            if (j > i && j < PRE_N) {
                float jx1 = bx1[j], jy1 = by1[j], jx2 = bx2[j], jy2 = by2[j];
                float ix1 = fmaxf(ax1, jx1), iy1 = fmaxf(ay1, jy1);
                float ix2 = fminf(ax2, jx2), iy2 = fminf(ay2, jy2);
                float iw = fmaxf(ix2 - ix1, 0.f);
                float ih = fmaxf(iy2 - iy1, 0.f);
                float inter = iw * ih;
                float barea = (jx2 - jx1) * (jy2 - jy1);
                float iou = inter / (aarea + barea - inter + 1e-9f);
                sup = iou > 0.7f;
            }
            unsigned long long m = __ballot(sup);
            if (lane == 0) supm[((size_t)b * PRE_N + i) * 32 + jw] = m;
        }
    }
}

// ---------------- serial NMS scan: visit kept boxes only ----------------
__global__ __launch_bounds__(64) void nms_scan_kernel(const float* __restrict__ top_s,
                                                      const unsigned long long* __restrict__ supm,
                                                      unsigned int* __restrict__ keepout) {
    int b = blockIdx.x;
    int lane = threadIdx.x;
    unsigned int mw = 0;          // remaining candidates, lane covers i in [lane*32, lane*32+32)
    for (int q = 0; q < 32; ++q) {
        int i = lane * 32 + q;
        if (top_s[b * PRE_N + i] > 0.f) mw |= (1u << q);
    }
    const unsigned int* sup32 = (const unsigned int*)(supm + (size_t)b * PRE_N * 32);
    unsigned int kf = 0;
    while (true) {
        unsigned long long bal = __ballot(mw != 0u);
        if (bal == 0ull) break;
        int fl = __builtin_ctzll(bal);
        unsigned int mfl = (unsigned int)__shfl((int)mw, fl);
        int q = __builtin_ctz(mfl);
        int i = fl * 32 + q;
        if (lane == fl) { kf |= (1u << q); mw &= ~(1u << q); }
        mw &= ~sup32[(size_t)i * 64 + lane];
    }
    keepout[b * 64 + lane] = kf;
}

// ---------------- final stable top-100 ----------------
__global__ __launch_bounds__(256) void finalize_kernel(const float* __restrict__ top_boxes,
                                                       const float* __restrict__ top_s,
                                                       const unsigned int* __restrict__ keepin,
                                                       float* __restrict__ out) {
    int b = blockIdx.x;
    int t = threadIdx.x;
    __shared__ unsigned int kw[64];
    __shared__ int wpre[65];
    if (t < 64) kw[t] = keepin[b * 64 + t];
    __syncthreads();
    if (t == 0) {
        int run = 0;
        for (int w = 0; w < 64; ++w) { wpre[w] = run; run += __popc(kw[w]); }
        wpre[64] = run;
    }
    __syncthreads();
    int total = wpre[64];
    float* out_boxes  = out;
    float* out_scores = out + NB * POST_N * 4;
    for (int i = t; i < PRE_N; i += 256) {
        unsigned int w = kw[i >> 5];
        bool kept = (w >> (i & 31)) & 1u;
        int rk = wpre[i >> 5] + __popc(w & ((1u << (i & 31)) - 1u));
        int pos = kept ? rk : total + (i - rk);
        if (pos < POST_N) {
            out_scores[b * POST_N + pos] = kept ? top_s[b * PRE_N + i] : -1.0f;
            ((float4*)out_boxes)[b * POST_N + pos] = ((const float4*)top_boxes)[b * PRE_N + i];
        }
    }
}

// ---------------- launch ----------------
extern "C" void kernel_launch(void* const* d_in, const int* in_sizes, int n_in,
                              void* d_out, int out_size, void* d_ws, size_t ws_size,
                              hipStream_t stream) {
    const float* features = (const float*)d_in[0];
    const float* W1 = (const float*)d_in[1];
    const float* b1 = (const float*)d_in[2];
    const float* W2 = (const float*)d_in[3];
    const float* b2 = (const float*)d_in[4];
    const float* W3 = (const float*)d_in[5];
    const float* b3 = (const float*)d_in[6];
    float* out = (float*)d_out;
    char* ws = (char*)d_ws;

    float* t_buf   = (float*)(ws + OFF_T);
    float* boxes   = (float*)(ws + OFF_BOXES);
    float* mscores = (float*)(ws + OFF_MS);
    unsigned long long* keys = (unsigned long long*)(ws + OFF_KEYS);
    float* top_boxes = (float*)(ws + OFF_TBOX);
    float* top_s     = (float*)(ws + OFF_TS);
    unsigned long long* supm = (unsigned long long*)(ws + OFF_SUP);
    unsigned int* keep = (unsigned int*)(ws + OFF_KEEP);
    unsigned short* FPh = (unsigned short*)(ws + OFF_PH);
    unsigned short* FPl = (unsigned short*)(ws + OFF_PL);
    unsigned short* WPh = (unsigned short*)(ws + OFF_WH);
    unsigned short* WPl = (unsigned short*)(ws + OFF_WL);

    prep_feat<<<5408, 256, 0, stream>>>(features, FPh, FPl);
    prep_w<<<128, 256, 0, stream>>>(W1, WPh, WPl);
    conv_mfma<<<832, 256, 0, stream>>>(FPh, FPl, WPh, WPl, b1, t_buf);
    proj_decode_mfma<<<157, 256, 0, stream>>>(t_buf, W2, b2, W3, b3, boxes, mscores, keys);
    select_sort_kernel<<<NB, 256, 0, stream>>>(keys, boxes, mscores, top_boxes, top_s);
    sup_kernel<<<NB * 125, 256, 0, stream>>>(top_boxes, supm);
    nms_scan_kernel<<<NB, 64, 0, stream>>>(top_s, supm, keep);
    finalize_kernel<<<NB, 256, 0, stream>>>(top_boxes, top_s, keep, out);
}

// Round 5
// 1217.139 us; speedup vs baseline: 13.7130x; 1.1316x over previous
//
#include <hip/hip_runtime.h>
#include <cstdint>

#define NB 8
#define CIN 1024
#define HDIM 50
#define WDIM 50
#define COUT 512
#define NA 9
#define NANCH (HDIM*WDIM*NA)   /* 22500 */
#define PRE_N 2000
#define POST_N 100

typedef __attribute__((ext_vector_type(8))) short bf16x8;
typedef __attribute__((ext_vector_type(4))) float f32x4;
typedef __attribute__((ext_vector_type(16))) float f32x16;
typedef __attribute__((ext_vector_type(8))) unsigned short ushort8v;

// ---------------- workspace layout (bytes) ----------------
// t planes (bf16 hi/lo) in proj-A-frag order: [pxblk157][cchunk16][mf8][q4][pxl16][j8]
constexpr size_t TPLANE    = 20578304;                   // 157*16*4096 shorts * 2B
constexpr size_t OFF_TPH   = 0;
constexpr size_t OFF_TPL   = OFF_TPH + TPLANE;           // 20,578,304
constexpr size_t OFF_BOXES = 41156608;                   // 8*22500*4 f32
constexpr size_t OFF_MS    = OFF_BOXES + 2880000;        // 8*22500 f32
constexpr size_t OFF_KEYS  = OFF_MS + 720000;            // 8*22500 u64
constexpr size_t OFF_TBOX  = OFF_KEYS + 1440000;         // 8*2000*4 f32
constexpr size_t OFF_TS    = OFF_TBOX + 256000;          // 8*2000 f32
constexpr size_t OFF_SUP   = OFF_TS + 64000;             // 8*2000*32 u64
constexpr size_t OFF_KEEP  = OFF_SUP + 4096000;          // 8*64 u32
// feature planes: [b8][cic64][rr52][lk2][cc52][ci8] bf16 (rr/cc include zero halo)
constexpr size_t PPLANE    = 44318720;                   // 44,302,336 used + slack
constexpr size_t OFF_PH    = 50614656;
constexpr size_t OFF_PL    = OFF_PH + PPLANE;
// weight planes: [cot8][cic64][tap9][lk2][co64][ci8] bf16
constexpr size_t WPLANE    = 9437184;
constexpr size_t OFF_WH    = OFF_PL + PPLANE;
constexpr size_t OFF_WL    = OFF_WH + WPLANE;
// end ~158.1 MB

__device__ __forceinline__ void split2bf16(float v, unsigned short &hi, unsigned short &lo) {
    unsigned int u = __float_as_uint(v);
    unsigned int r = u + 0x7FFFu + ((u >> 16) & 1u);
    hi = (unsigned short)(r >> 16);
    float hf = __uint_as_float(((unsigned int)hi) << 16);
    float lf = v - hf;
    unsigned int u2 = __float_as_uint(lf);
    unsigned int r2 = u2 + 0x7FFFu + ((u2 >> 16) & 1u);
    lo = (unsigned short)(r2 >> 16);
}

__device__ __forceinline__ void gl_lds(const unsigned short* g, unsigned short* l) {
    __builtin_amdgcn_global_load_lds(
        (const __attribute__((address_space(1))) unsigned int*)(const void*)g,
        (__attribute__((address_space(3))) unsigned int*)(void*)l,
        16, 0, 0);
}

// ---------------- preprocess: feature -> hi/lo bf16 planes [b][cic][rr][lk][cc][8] ----------------
// thread = one (b,cic,rr,cc), handles 16 ci. grid: 8*64*52*52/256 = 5408
__global__ __launch_bounds__(256) void prep_feat(const float* __restrict__ f,
                                                 unsigned short* __restrict__ Ph,
                                                 unsigned short* __restrict__ Pl) {
    int id = blockIdx.x * 256 + threadIdx.x;
    int cc = id % 52; int r = id / 52;
    int rr = r % 52;  r /= 52;
    int cic = r % 64; int b = r / 64;
    int h = rr - 1, w = cc - 1;
    bool inb = (h >= 0 && h < HDIM && w >= 0 && w < WDIM);
    ushort8v hv0, lv0, hv1, lv1;
#pragma unroll
    for (int j = 0; j < 16; ++j) {
        float v = 0.f;
        if (inb) v = f[(((size_t)b * CIN + cic * 16 + j) * HDIM + h) * WDIM + w];
        unsigned short hi, lo;
        split2bf16(v, hi, lo);
        if (j < 8) { hv0[j] = hi; lv0[j] = lo; }
        else       { hv1[j - 8] = hi; lv1[j - 8] = lo; }
    }
    size_t rowb = (size_t)((b * 64 + cic) * 52 + rr) * 832;   // shorts per row-block
    *(ushort8v*)&Ph[rowb + cc * 8]       = hv0;   // lk=0
    *(ushort8v*)&Ph[rowb + 416 + cc * 8] = hv1;   // lk=1
    *(ushort8v*)&Pl[rowb + cc * 8]       = lv0;
    *(ushort8v*)&Pl[rowb + 416 + cc * 8] = lv1;
}

// ---------------- preprocess: W1 -> hi/lo planes [cot][cic][tap][lk][co][8] ----------------
// thread = one (cot,cic,co). grid: 8*64*64/256 = 128
__global__ __launch_bounds__(256) void prep_w(const float* __restrict__ W1,
                                              unsigned short* __restrict__ Wh,
                                              unsigned short* __restrict__ Wl) {
    int id = blockIdx.x * 256 + threadIdx.x;
    int co = id % 64; int r = id / 64;
    int cic = r % 64; int cot = r / 64;
    int cog = cot * 64 + co;
    const float* src = W1 + ((size_t)cog * CIN + cic * 16) * 9;   // 144 consecutive floats
    float v[144];
#pragma unroll
    for (int i = 0; i < 36; ++i) {
        float4 x = ((const float4*)src)[i];
        v[i * 4 + 0] = x.x; v[i * 4 + 1] = x.y; v[i * 4 + 2] = x.z; v[i * 4 + 3] = x.w;
    }
#pragma unroll
    for (int tap = 0; tap < 9; ++tap) {
        ushort8v hv0, lv0, hv1, lv1;
#pragma unroll
        for (int j = 0; j < 16; ++j) {
            unsigned short hi, lo;
            split2bf16(v[j * 9 + tap], hi, lo);
            if (j < 8) { hv0[j] = hi; lv0[j] = lo; }
            else       { hv1[j - 8] = hi; lv1[j - 8] = lo; }
        }
        size_t base = (size_t)(((cot * 64 + cic) * 9 + tap) * 2) * 512;  // shorts
        *(ushort8v*)&Wh[base + co * 8]       = hv0;   // lk=0
        *(ushort8v*)&Wh[base + 512 + co * 8] = hv1;   // lk=1
        *(ushort8v*)&Wl[base + co * 8]       = lv0;
        *(ushort8v*)&Wl[base + 512 + co * 8] = lv1;
    }
}

// ---------------- conv 3x3 via split-bf16 MFMA 32x32x16, conflict-free LDS ----------------
// grid: 832 = b(8) x mt(13) x cot(8). Block: 4 rows x 64 cols(M) x 64 co(N).
__global__ __launch_bounds__(256, 2) void conv_mfma(const unsigned short* __restrict__ FPh,
                                                    const unsigned short* __restrict__ FPl,
                                                    const unsigned short* __restrict__ WPh,
                                                    const unsigned short* __restrict__ WPl,
                                                    const float* __restrict__ b1,
                                                    unsigned short* __restrict__ Tph,
                                                    unsigned short* __restrict__ Tpl) {
    __shared__ unsigned short sAh[5120], sAl[5120];   // [row6][lk2][cc52][8] + slack
    __shared__ unsigned short sBh[9216], sBl[9216];   // [tap9][lk2][co64][8]

    int blk = blockIdx.x;
    int cot = blk & 7;
    int mt  = (blk >> 3) % 13;
    int b   = blk / 104;
    int co0 = cot * 64;
    int r0  = mt * 4;

    int t = threadIdx.x, wv = t >> 6, ln = t & 63;
    int lm = ln & 31, lk = ln >> 5;

    f32x16 acc[2][2];
#pragma unroll
    for (int jm = 0; jm < 2; ++jm)
#pragma unroll
        for (int jn = 0; jn < 2; ++jn)
#pragma unroll
            for (int rg = 0; rg < 16; ++rg) acc[jm][jn][rg] = 0.f;

#pragma unroll 1
    for (int cic = 0; cic < 64; ++cic) {
        __syncthreads();
        const unsigned short* wH = WPh + (size_t)(cot * 64 + cic) * 9216;
        const unsigned short* wL = WPl + (size_t)(cot * 64 + cic) * 9216;
        const unsigned short* aH = FPh + (size_t)((b * 64 + cic) * 52 + r0) * 832;
        const unsigned short* aL = FPl + (size_t)((b * 64 + cic) * 52 + r0) * 832;
        if (wv == 0) {
#pragma unroll
            for (int s = 0; s < 14; ++s) gl_lds(wH + s * 512 + ln * 8, &sBh[s * 512]);
        } else if (wv == 1) {
#pragma unroll
            for (int s = 14; s < 18; ++s) gl_lds(wH + s * 512 + ln * 8, &sBh[s * 512]);
#pragma unroll
            for (int s = 0; s < 10; ++s) gl_lds(wL + s * 512 + ln * 8, &sBl[s * 512]);
        } else if (wv == 2) {
#pragma unroll
            for (int s = 10; s < 18; ++s) gl_lds(wL + s * 512 + ln * 8, &sBl[s * 512]);
#pragma unroll
            for (int s = 0; s < 6; ++s)  gl_lds(aH + s * 512 + ln * 8, &sAh[s * 512]);
        } else {
#pragma unroll
            for (int s = 6; s < 10; ++s) gl_lds(aH + s * 512 + ln * 8, &sAh[s * 512]);
#pragma unroll
            for (int s = 0; s < 10; ++s) gl_lds(aL + s * 512 + ln * 8, &sAl[s * 512]);
        }
        __syncthreads();

#pragma unroll
        for (int tap = 0; tap < 9; ++tap) {
            const int kh = tap / 3, kw = tap % 3;
            int arow = wv + kh;
            bf16x8 a[2][2], bb[2][2];
#pragma unroll
            for (int jm = 0; jm < 2; ++jm) {
                int cc = jm * 32 + lm + kw;
                if (cc > 51) cc = 51;                  // pad lanes: clamp (dup = broadcast, free)
                int ad = ((arow * 2 + lk) * 52 + cc) * 8;
                a[jm][0] = *(const bf16x8*)&sAh[ad];
                a[jm][1] = *(const bf16x8*)&sAl[ad];
            }
#pragma unroll
            for (int jn = 0; jn < 2; ++jn) {
                int bd = ((tap * 2 + lk) * 64 + jn * 32 + lm) * 8;
                bb[jn][0] = *(const bf16x8*)&sBh[bd];
                bb[jn][1] = *(const bf16x8*)&sBl[bd];
            }
#pragma unroll
            for (int jm = 0; jm < 2; ++jm)
#pragma unroll
                for (int jn = 0; jn < 2; ++jn) {
                    acc[jm][jn] = __builtin_amdgcn_mfma_f32_32x32x16_bf16(a[jm][0], bb[jn][0], acc[jm][jn], 0, 0, 0);
                    acc[jm][jn] = __builtin_amdgcn_mfma_f32_32x32x16_bf16(a[jm][0], bb[jn][1], acc[jm][jn], 0, 0, 0);
                    acc[jm][jn] = __builtin_amdgcn_mfma_f32_32x32x16_bf16(a[jm][1], bb[jn][0], acc[jm][jn], 0, 0, 0);
                }
        }
    }

    // epilogue: bias+relu, split to bf16 hi/lo, store in proj-A-frag plane order
    int h = r0 + wv;
    if (h >= HDIM) return;
#pragma unroll
    for (int jn = 0; jn < 2; ++jn) {
        int co = co0 + jn * 32 + lm;
        float bv = b1[co];
#pragma unroll
        for (int jm = 0; jm < 2; ++jm) {
#pragma unroll
            for (int rg = 0; rg < 16; ++rg) {
                int w = jm * 32 + (rg & 3) + 8 * (rg >> 2) + 4 * lk;
                if (w < WDIM) {
                    float v = fmaxf(acc[jm][jn][rg] + bv, 0.f);
                    unsigned short hi, lo;
                    split2bf16(v, hi, lo);
                    int px = b * 2500 + h * 50 + w;
                    size_t sa = (((((size_t)(px >> 7) * 16 + (co >> 5)) * 8 + ((px >> 4) & 7)) * 4
                                  + ((co >> 3) & 3)) * 16 + (px & 15)) * 8 + (co & 7);
                    Tph[sa] = hi;
                    Tpl[sa] = lo;
                }
            }
        }
    }
}

// ---------------- projection (MFMA, planes staged via gl_lds) + decode + key build ----------------
// grid: 157 blocks x 256 thr. Block: 128 px(M) x 48 o(N, 45 used), K=512.
__global__ __launch_bounds__(256) void proj_decode_mfma(const unsigned short* __restrict__ Tph,
                                                        const unsigned short* __restrict__ Tpl,
                                                        const float* __restrict__ W2,
                                                        const float* __restrict__ b2,
                                                        const float* __restrict__ W3,
                                                        const float* __restrict__ b3,
                                                        float* __restrict__ boxes,
                                                        float* __restrict__ mscores,
                                                        unsigned long long* __restrict__ keys) {
    __shared__ unsigned short sTh[4096], sTl[4096];   // A frag-order [mf8][q4][pxl16][8]
    __shared__ unsigned short sWh[1536], sWl[1536];   // B frag-order [nf3][q4][ol16][8]
    __shared__ float pout[128 * 46];

    int blk = blockIdx.x;
    int px0 = blk * 128;
    int t = threadIdx.x, wv = t >> 6, ln = t & 63;
    int lm = ln & 15, q = ln >> 4;

    f32x4 acc[2][3];
#pragma unroll
    for (int jm = 0; jm < 2; ++jm)
#pragma unroll
        for (int nf = 0; nf < 3; ++nf) acc[jm][nf] = (f32x4){0.f, 0.f, 0.f, 0.f};

#pragma unroll 1
    for (int cc16 = 0; cc16 < 16; ++cc16) {
        __syncthreads();
        size_t base = ((size_t)blk * 16 + cc16) * 4096;
        if (wv == 0) {
#pragma unroll
            for (int s = 0; s < 4; ++s) gl_lds(Tph + base + s * 512 + ln * 8, &sTh[s * 512]);
        } else if (wv == 1) {
#pragma unroll
            for (int s = 4; s < 8; ++s) gl_lds(Tph + base + s * 512 + ln * 8, &sTh[s * 512]);
        } else if (wv == 2) {
#pragma unroll
            for (int s = 0; s < 4; ++s) gl_lds(Tpl + base + s * 512 + ln * 8, &sTl[s * 512]);
        } else {
#pragma unroll
            for (int s = 4; s < 8; ++s) gl_lds(Tpl + base + s * 512 + ln * 8, &sTl[s * 512]);
        }
        int c0 = cc16 * 32;
        for (int idx = t; idx < 1536; idx += 256) {   // B staging (tiny)
            int o = idx >> 5, ci = idx & 31;
            float v = 0.f;
            if (o < 36) v = W2[o * 512 + c0 + ci];
            else if (o < 45) v = W3[(o - 36) * 512 + c0 + ci];
            unsigned short hi, lo;
            split2bf16(v, hi, lo);
            int ad = (((o >> 4) * 4 + (ci >> 3)) * 16 + (o & 15)) * 8 + (ci & 7);
            sWh[ad] = hi; sWl[ad] = lo;
        }
        __syncthreads();

        bf16x8 a[2][2], bb[3][2];
#pragma unroll
        for (int jm = 0; jm < 2; ++jm) {
            int mf = wv * 2 + jm;
            int ad = ((mf * 4 + q) * 16 + lm) * 8;
            a[jm][0] = *(const bf16x8*)&sTh[ad];
            a[jm][1] = *(const bf16x8*)&sTl[ad];
        }
#pragma unroll
        for (int nf = 0; nf < 3; ++nf) {
            int ad = ((nf * 4 + q) * 16 + lm) * 8;
            bb[nf][0] = *(const bf16x8*)&sWh[ad];
            bb[nf][1] = *(const bf16x8*)&sWl[ad];
        }
#pragma unroll
        for (int jm = 0; jm < 2; ++jm)
#pragma unroll
            for (int nf = 0; nf < 3; ++nf) {
                acc[jm][nf] = __builtin_amdgcn_mfma_f32_16x16x32_bf16(a[jm][0], bb[nf][0], acc[jm][nf], 0, 0, 0);
                acc[jm][nf] = __builtin_amdgcn_mfma_f32_16x16x32_bf16(a[jm][0], bb[nf][1], acc[jm][nf], 0, 0, 0);
                acc[jm][nf] = __builtin_amdgcn_mfma_f32_16x16x32_bf16(a[jm][1], bb[nf][0], acc[jm][nf], 0, 0, 0);
            }
    }
    __syncthreads();
#pragma unroll
    for (int jm = 0; jm < 2; ++jm)
#pragma unroll
        for (int nf = 0; nf < 3; ++nf) {
            int o = nf * 16 + lm;
            if (o < 45) {
                float bias = (o < 36) ? b2[o] : b3[o - 36];
#pragma unroll
                for (int rg = 0; rg < 4; ++rg) {
                    int pxl = (wv * 2 + jm) * 16 + q * 4 + rg;
                    pout[pxl * 46 + o] = acc[jm][nf][rg] + bias;
                }
            }
        }
    __syncthreads();

    const float AW[9] = {90.50966799187809f, 128.0f, 181.01933598375618f,
                         181.01933598375618f, 256.0f, 362.03867196751236f,
                         362.03867196751236f, 512.0f, 724.0773439350247f};
    const float AH[9] = {181.01933598375618f, 128.0f, 90.50966799187809f,
                         362.03867196751236f, 256.0f, 181.01933598375618f,
                         724.0773439350247f, 512.0f, 362.03867196751236f};
    const float CLIPV = 4.135166556742356f;
    const float IMG = 1600.0f;

    for (int it = t; it < 128 * 9; it += 256) {
        int pxl = it / 9, a = it - pxl * 9;
        int pxg = px0 + pxl;
        if (pxg >= 20000) continue;
        int b = pxg / 2500, rem = pxg % 2500;
        int h = rem / 50, w = rem % 50;

        float tx = pout[pxl * 46 + a * 4 + 0];
        float ty = pout[pxl * 46 + a * 4 + 1];
        float tw = pout[pxl * 46 + a * 4 + 2];
        float th = pout[pxl * 46 + a * 4 + 3];
        float lg = pout[pxl * 46 + 36 + a];

        float s = 1.0f / (1.0f + expf(-lg));

        float cx = ((float)w + 0.5f) * 32.0f;
        float cy = ((float)h + 0.5f) * 32.0f;
        float x1a = cx - 0.5f * AW[a];
        float x2a = cx + 0.5f * AW[a];
        float y1a = cy - 0.5f * AH[a];
        float y2a = cy + 0.5f * AH[a];
        float waf = x2a - x1a;
        float haf = y2a - y1a;
        float cxa = x1a + 0.5f * waf;
        float cya = y1a + 0.5f * haf;

        float twc = tw < CLIPV ? tw : CLIPV;
        float thc = th < CLIPV ? th : CLIPV;
        float pxc = tx * waf + cxa;
        float pyc = ty * haf + cya;
        float pw  = expf(twc) * waf;
        float ph  = expf(thc) * haf;

        float x1 = pxc - 0.5f * pw;
        float y1 = pyc - 0.5f * ph;
        float x2 = pxc + 0.5f * pw;
        float y2 = pyc + 0.5f * ph;
        x1 = fminf(fmaxf(x1, 0.f), IMG);
        y1 = fminf(fmaxf(y1, 0.f), IMG);
        x2 = fminf(fmaxf(x2, 0.f), IMG);
        y2 = fminf(fmaxf(y2, 0.f), IMG);

        float bw = x2 - x1, bh = y2 - y1;
        bool valid = (s >= 0.1f) && (bw > 16.0f) && (bh > 16.0f);
        float m = valid ? s : -1.0f;

        int idx = (h * WDIM + w) * NA + a;
        size_t gi = (size_t)b * NANCH + idx;
        ((float4*)boxes)[gi] = make_float4(x1, y1, x2, y2);
        mscores[gi] = m;
        unsigned int u = __float_as_uint(m);
        unsigned int k32 = (u & 0x80000000u) ? ~u : (u | 0x80000000u);
        keys[gi] = ((unsigned long long)k32 << 15) | (unsigned long long)(32767 - idx);
    }
}

// ---------------- exact stable top-2000 (47-bit radix select, 4 passes + bitonic) ----------------
__global__ __launch_bounds__(256) void select_sort_kernel(const unsigned long long* __restrict__ keys,
                                                          const float* __restrict__ boxes,
                                                          const float* __restrict__ mscores,
                                                          float* __restrict__ top_boxes,
                                                          float* __restrict__ top_s) {
    int b = blockIdx.x;
    int t = threadIdx.x;
    const unsigned long long* kb = keys + (size_t)b * NANCH;

    __shared__ unsigned int hist[4096];
    __shared__ unsigned int gs[256];
    __shared__ int s_chosen, s_rnew;
    __shared__ unsigned int s_cnt;
    __shared__ unsigned long long skeys[2048];

    const int widths[4] = {12, 12, 12, 11};
    unsigned long long prefix = 0;
    int bitsdone = 0;
    int r = PRE_N;

    for (int p = 0; p < 4; ++p) {
        int width = widths[p];
        int bins = 1 << width;
        int shift = 47 - bitsdone - width;
        for (int i = t; i < bins; i += 256) hist[i] = 0;
        __syncthreads();
        for (int i = t; i < NANCH; i += 256) {
            unsigned long long k = kb[i];
            bool ok = (k >> (47 - bitsdone)) == prefix;
            if (ok) atomicAdd(&hist[(unsigned)((k >> shift) & (unsigned long long)(bins - 1))], 1u);
        }
        __syncthreads();
        int G = bins >> 8;
        unsigned int gsum = 0;
        for (int g = 0; g < G; ++g) gsum += hist[t * G + g];
        gs[t] = gsum;
        __syncthreads();
        if (t == 0) {
            int acc = 0, chosen = 0, rnew = 1;
            for (int g = 255; g >= 0; --g) {
                int sgv = (int)gs[g];
                if (acc + sgv >= r) {
                    for (int d = g * G + G - 1; d >= g * G; --d) {
                        int hv = (int)hist[d];
                        if (acc + hv >= r) { chosen = d; rnew = r - acc; break; }
                        acc += hv;
                    }
                    break;
                }
                acc += sgv;
            }
            s_chosen = chosen;
            s_rnew = rnew;
        }
        __syncthreads();
        prefix = (prefix << width) | (unsigned long long)s_chosen;
        bitsdone += width;
        r = s_rnew;
        __syncthreads();
    }
    unsigned long long Kst = prefix;   // exact rank-2000 key (47-bit)

    if (t == 0) s_cnt = 0;
    __syncthreads();
    for (int i = t; i < NANCH; i += 256) {
        unsigned long long k = kb[i];
        if (k >= Kst) {
            unsigned int p = atomicAdd(&s_cnt, 1u);
            if (p < 2048) skeys[p] = k;
        }
    }
    __syncthreads();
    unsigned int cnt = s_cnt;
    for (int i = t; i < 2048; i += 256)
        if (i >= (int)cnt) skeys[i] = 0ull;
    for (int k = 2; k <= 2048; k <<= 1) {
        for (int j = k >> 1; j > 0; j >>= 1) {
            __syncthreads();
            for (int i = t; i < 2048; i += 256) {
                int l = i ^ j;
                if (l > i) {
                    unsigned long long a = skeys[i], c = skeys[l];
                    bool up = ((i & k) == 0);
                    if (up ? (a < c) : (a > c)) { skeys[i] = c; skeys[l] = a; }
                }
            }
        }
    }
    __syncthreads();
    for (int i = t; i < PRE_N; i += 256) {
        unsigned long long k = skeys[i];
        unsigned int idx = 32767u - (unsigned int)(k & 32767ull);
        size_t gi = (size_t)b * NANCH + idx;
        top_s[b * PRE_N + i] = mscores[gi];
        ((float4*)top_boxes)[b * PRE_N + i] = ((const float4*)boxes)[gi];
    }
}

// ---------------- IoU suppression bit-matrix ----------------
__global__ __launch_bounds__(256) void sup_kernel(const float* __restrict__ top_boxes,
                                                  unsigned long long* __restrict__ supm) {
    int blk = blockIdx.x;
    int b = blk / 125;
    int chunk = blk % 125;
    int t = threadIdx.x;

    __shared__ float bx1[PRE_N], by1[PRE_N], bx2[PRE_N], by2[PRE_N];
    for (int i = t; i < PRE_N; i += 256) {
        float4 v = ((const float4*)top_boxes)[b * PRE_N + i];
        bx1[i] = v.x; by1[i] = v.y; bx2[i] = v.z; by2[i] = v.w;
    }
    __syncthreads();

    int wave = t >> 6, lane = t & 63;
    for (int rr = 0; rr < 4; ++rr) {
        int i = chunk * 16 + wave * 4 + rr;
        float ax1 = bx1[i], ay1 = by1[i], ax2 = bx2[i], ay2 = by2[i];
        float aarea = (ax2 - ax1) * (ay2 - ay1);
        for (int jw = 0; jw < 32; ++jw) {
            int j = jw * 64 + lane;
            bool sup = false;
            if (j > i && j < PRE_N) {
                float jx1 = bx1[j], jy1 = by1[j], jx2 = bx2[j], jy2 = by2[j];
                float ix1 = fmaxf(ax1, jx1), iy1 = fmaxf(ay1, jy1);
                float ix2 = fminf(ax2, jx2), iy2 = fminf(ay2, jy2);
                float iw = fmaxf(ix2 - ix1, 0.f);
                float ih = fmaxf(iy2 - iy1, 0.f);
                float inter = iw * ih;
                float barea = (jx2 - jx1) * (jy2 - jy1);
                float iou = inter / (aarea + barea - inter + 1e-9f);
                sup = iou > 0.7f;
            }
            unsigned long long m = __ballot(sup);
            if (lane == 0) supm[((size_t)b * PRE_N + i) * 32 + jw] = m;
        }
    }
}

// ---------------- tiled NMS scan: registers intra-tile, batched OR inter-tile ----------------
__global__ __launch_bounds__(64) void nms_scan_kernel(const float* __restrict__ top_s,
                                                      const unsigned long long* __restrict__ supm,
                                                      unsigned int* __restrict__ keepout) {
    int b = blockIdx.x;
    int lane = threadIdx.x;
    unsigned int alive = 0;      // lane covers cols [lane*32, +32)
    for (int q = 0; q < 32; ++q) {
        int i = lane * 32 + q;
        if (i < PRE_N && top_s[b * PRE_N + i] > 0.f) alive |= (1u << q);
    }
    const unsigned long long* sm = supm + (size_t)b * PRE_N * 32;
    const unsigned int* sup32 = (const unsigned int*)sm;

    for (int tt = 0; tt < 32; ++tt) {
        unsigned int alo = __shfl(alive, 2 * tt);
        unsigned int ahi = __shfl(alive, 2 * tt + 1);
        unsigned long long talive = (unsigned long long)alo | ((unsigned long long)ahi << 32);
        int i_row = tt * 64 + lane;
        unsigned long long rm = (i_row < PRE_N) ? sm[(size_t)i_row * 32 + tt] : 0ull;

        unsigned long long kept = 0, rem = talive;
        while (rem) {
            int j = __builtin_ctzll(rem);
            kept |= (1ull << j);
            unsigned long long rmj = __shfl(rm, j);
            rem &= ~rmj;
            rem &= ~(1ull << j);
        }

        unsigned int oracc = 0;
        unsigned long long kk = kept;
        while (kk) {
            int j0 = __builtin_ctzll(kk); kk &= kk - 1;
            int j1 = -1, j2 = -1, j3 = -1;
            if (kk) { j1 = __builtin_ctzll(kk); kk &= kk - 1; }
            if (kk) { j2 = __builtin_ctzll(kk); kk &= kk - 1; }
            if (kk) { j3 = __builtin_ctzll(kk); kk &= kk - 1; }
            unsigned int v0 = sup32[(size_t)(tt * 64 + j0) * 64 + lane];
            unsigned int v1 = (j1 >= 0) ? sup32[(size_t)(tt * 64 + j1) * 64 + lane] : 0u;
            unsigned int v2 = (j2 >= 0) ? sup32[(size_t)(tt * 64 + j2) * 64 + lane] : 0u;
            unsigned int v3 = (j3 >= 0) ? sup32[(size_t)(tt * 64 + j3) * 64 + lane] : 0u;
            oracc |= v0 | v1 | v2 | v3;
        }
        alive &= ~oracc;
        if (lane == 2 * tt)     alive = (unsigned int)kept;
        if (lane == 2 * tt + 1) alive = (unsigned int)(kept >> 32);
    }
    keepout[b * 64 + lane] = alive;
}

// ---------------- final stable top-100 ----------------
__global__ __launch_bounds__(256) void finalize_kernel(const float* __restrict__ top_boxes,
                                                       const float* __restrict__ top_s,
                                                       const unsigned int* __restrict__ keepin,
                                                       float* __restrict__ out) {
    int b = blockIdx.x;
    int t = threadIdx.x;
    __shared__ unsigned int kw[64];
    __shared__ int wpre[65];
    if (t < 64) kw[t] = keepin[b * 64 + t];
    __syncthreads();
    if (t == 0) {
        int run = 0;
        for (int w = 0; w < 64; ++w) { wpre[w] = run; run += __popc(kw[w]); }
        wpre[64] = run;
    }
    __syncthreads();
    int total = wpre[64];
    float* out_boxes  = out;
    float* out_scores = out + NB * POST_N * 4;
    for (int i = t; i < PRE_N; i += 256) {
        unsigned int w = kw[i >> 5];
        bool kept = (w >> (i & 31)) & 1u;
        int rk = wpre[i >> 5] + __popc(w & ((1u << (i & 31)) - 1u));
        int pos = kept ? rk : total + (i - rk);
        if (pos < POST_N) {
            out_scores[b * POST_N + pos] = kept ? top_s[b * PRE_N + i] : -1.0f;
            ((float4*)out_boxes)[b * POST_N + pos] = ((const float4*)top_boxes)[b * PRE_N + i];
        }
    }
}

// ---------------- launch ----------------
extern "C" void kernel_launch(void* const* d_in, const int* in_sizes, int n_in,
                              void* d_out, int out_size, void* d_ws, size_t ws_size,
                              hipStream_t stream) {
    const float* features = (const float*)d_in[0];
    const float* W1 = (const float*)d_in[1];
    const float* b1 = (const float*)d_in[2];
    const float* W2 = (const float*)d_in[3];
    const float* b2 = (const float*)d_in[4];
    const float* W3 = (const float*)d_in[5];
    const float* b3 = (const float*)d_in[6];
    float* out = (float*)d_out;
    char* ws = (char*)d_ws;

    unsigned short* Tph = (unsigned short*)(ws + OFF_TPH);
    unsigned short* Tpl = (unsigned short*)(ws + OFF_TPL);
    float* boxes   = (float*)(ws + OFF_BOXES);
    float* mscores = (float*)(ws + OFF_MS);
    unsigned long long* keys = (unsigned long long*)(ws + OFF_KEYS);
    float* top_boxes = (float*)(ws + OFF_TBOX);
    float* top_s     = (float*)(ws + OFF_TS);
    unsigned long long* supm = (unsigned long long*)(ws + OFF_SUP);
    unsigned int* keep = (unsigned int*)(ws + OFF_KEEP);
    unsigned short* FPh = (unsigned short*)(ws + OFF_PH);
    unsigned short* FPl = (unsigned short*)(ws + OFF_PL);
    unsigned short* WPh = (unsigned short*)(ws + OFF_WH);
    unsigned short* WPl = (unsigned short*)(ws + OFF_WL);

    prep_feat<<<5408, 256, 0, stream>>>(features, FPh, FPl);
    prep_w<<<128, 256, 0, stream>>>(W1, WPh, WPl);
    conv_mfma<<<832, 256, 0, stream>>>(FPh, FPl, WPh, WPl, b1, Tph, Tpl);
    proj_decode_mfma<<<157, 256, 0, stream>>>(Tph, Tpl, W2, b2, W3, b3, boxes, mscores, keys);
    select_sort_kernel<<<NB, 256, 0, stream>>>(keys, boxes, mscores, top_boxes, top_s);
    sup_kernel<<<NB * 125, 256, 0, stream>>>(top_boxes, supm);
    nms_scan_kernel<<<NB, 64, 0, stream>>>(top_s, supm, keep);
    finalize_kernel<<<NB, 256, 0, stream>>>(top_boxes, top_s, keep, out);
}